// Round 13
// baseline (289.520 us; speedup 1.0000x reference)
//
#include <hip/hip_runtime.h>
#include <hip/hip_bf16.h>

#define TSEQ 2048
#define CDIM 1024
#define NH 16
#define HS 64

typedef __attribute__((ext_vector_type(8))) short bf16x8;
typedef __attribute__((ext_vector_type(4))) float f32x4;
typedef __attribute__((ext_vector_type(16))) float f32x16;

__device__ inline void gload16(const void* g, void* l) {
    __builtin_amdgcn_global_load_lds((const __attribute__((address_space(1))) void*)g,
                                     (__attribute__((address_space(3))) void*)l, 16, 0, 0);
}

__device__ inline unsigned packbf(float a, float b) {
    union { __hip_bfloat162 h; unsigned u; } cv;
    cv.h = __float22bfloat162_rn(make_float2(a, b));
    return cv.u;
}

// ---------- elementwise f32 -> bf16 ----------
__global__ __launch_bounds__(256)
void conv_bf16(const float* __restrict__ in, __hip_bfloat16* __restrict__ out, int n) {
    int i = (blockIdx.x * 256 + threadIdx.x) * 4;
    if (i + 3 < n) {
        float4 v = *(const float4*)(in + i);
        union { ushort4 u; __hip_bfloat16 h[4]; } o;
        o.h[0] = __float2bfloat16(v.x);
        o.h[1] = __float2bfloat16(v.y);
        o.h[2] = __float2bfloat16(v.z);
        o.h[3] = __float2bfloat16(v.w);
        *(ushort4*)((unsigned short*)out + i) = o.u;
    }
}

// ---------- exp(b2) precompute ----------
__global__ __launch_bounds__(256)
void exp_b2(const float* __restrict__ b2, float* __restrict__ eb2, int n) {
    int i = blockIdx.x * 256 + threadIdx.x;
    if (i < n) eb2[i] = __expf(b2[i]);
}

// ---------- tiled transpose (+convert) : in [R][C] f32 -> out [C][R] bf16 ----------
__global__ __launch_bounds__(256)
void transpose_to_bf16(const float* __restrict__ in, __hip_bfloat16* __restrict__ out,
                       int R, int C) {
    __shared__ float t[32][33];
    const int tx = threadIdx.x & 31, ty = threadIdx.x >> 5;  // 32 x 8
    const int r0 = blockIdx.y * 32, c0 = blockIdx.x * 32;
    #pragma unroll
    for (int i = 0; i < 32; i += 8)
        t[ty + i][tx] = in[(size_t)(r0 + ty + i) * C + c0 + tx];
    __syncthreads();
    #pragma unroll
    for (int i = 0; i < 32; i += 8)
        out[(size_t)(c0 + ty + i) * R + r0 + tx] = __float2bfloat16(t[tx][ty + i]);
}

// ---------- fused 3x 1024x1024 transpose (W1, Wv, Wp) ----------
__global__ __launch_bounds__(256)
void transpose3_to_bf16(const float* __restrict__ W1, const float* __restrict__ Wv,
                        const float* __restrict__ Wp, __hip_bfloat16* __restrict__ o1,
                        __hip_bfloat16* __restrict__ o2, __hip_bfloat16* __restrict__ o3) {
    __shared__ float t[32][33];
    const float* in = blockIdx.z == 0 ? W1 : (blockIdx.z == 1 ? Wv : Wp);
    __hip_bfloat16* out = blockIdx.z == 0 ? o1 : (blockIdx.z == 1 ? o2 : o3);
    const int tx = threadIdx.x & 31, ty = threadIdx.x >> 5;
    const int r0 = blockIdx.y * 32, c0 = blockIdx.x * 32;
    #pragma unroll
    for (int i = 0; i < 32; i += 8)
        t[ty + i][tx] = in[(size_t)(r0 + ty + i) * CDIM + c0 + tx];
    __syncthreads();
    #pragma unroll
    for (int i = 0; i < 32; i += 8)
        out[(size_t)(c0 + ty + i) * CDIM + r0 + tx] = __float2bfloat16(t[tx][ty + i]);
}

// ---------- fused QV GEMM: [H | Vblk] = x @ [W1 | Wv] ----------
// V written to BLOCKED layout Vblk[h][b][kt][d][64] with sigma (swap t-bits
// 2,3) applied within each 64-panel so the attention kernel's PV B-operand
// lines up with direct-packed P fragments (no shfl).
__global__ __launch_bounds__(256, 2)
void gemm_qv(const __hip_bfloat16* __restrict__ X, const __hip_bfloat16* __restrict__ W,
             const float* __restrict__ bw1, const float* __restrict__ b1,
             const float* __restrict__ bv, __hip_bfloat16* __restrict__ Hb,
             __hip_bfloat16* __restrict__ Vblk, int M)
{
    __shared__ __align__(16) __hip_bfloat16 As[128 * 32];
    __shared__ __align__(16) __hip_bfloat16 Bs[128 * 32];
    const int tid = threadIdx.x, wave = tid >> 6, lane = tid & 63;
    const int wr = wave >> 1, wc = wave & 1, l15 = lane & 15, l4 = lane >> 4;
    const int m0 = blockIdx.y * 128, n0 = blockIdx.x * 128;
    const int K = CDIM;
    const int Bb = M >> 11;                       // batches (T=2048)
    const int srow = wave * 32 + (lane >> 2), scol = (lane & 3) * 8;
    const __hip_bfloat16* xg = X + (size_t)(m0 + srow) * K + scol;
    const __hip_bfloat16* wg = W + (size_t)(n0 + srow) * K + scol;
    __hip_bfloat16* la = &As[wave * 32 * 32];
    __hip_bfloat16* lb = &Bs[wave * 32 * 32];

    f32x4 acc[4][4] = {};
    for (int k0 = 0; k0 < K; k0 += 32) {
        __syncthreads();
        gload16(xg + k0, la);
        gload16(xg + k0 + (size_t)16 * K, la + 16 * 32);
        gload16(wg + k0, lb);
        gload16(wg + k0 + (size_t)16 * K, lb + 16 * 32);
        __syncthreads();
        bf16x8 af[4], bfr[4];
        #pragma unroll
        for (int f = 0; f < 4; f++) af[f]  = *(const bf16x8*)&As[(wr * 64 + f * 16 + l15) * 32 + l4 * 8];
        #pragma unroll
        for (int f = 0; f < 4; f++) bfr[f] = *(const bf16x8*)&Bs[(wc * 64 + f * 16 + l15) * 32 + l4 * 8];
        #pragma unroll
        for (int fr = 0; fr < 4; fr++)
            #pragma unroll
            for (int fc = 0; fc < 4; fc++)
                acc[fr][fc] = __builtin_amdgcn_mfma_f32_16x16x32_bf16(af[fr], bfr[fc], acc[fr][fc], 0, 0, 0);
    }

    const bool isH = (n0 < CDIM);
    const int sl4 = ((l4 & 1) << 1) | (l4 >> 1);   // sigma: swap t-bits 2,3
    if (isH) {
        #pragma unroll
        for (int fc = 0; fc < 4; fc++) {
            const int col = n0 + wc * 64 + fc * 16 + l15;
            const float bias = bw1[col] + b1[col & (HS - 1)];
            #pragma unroll
            for (int fr = 0; fr < 4; fr++)
                #pragma unroll
                for (int r = 0; r < 4; r++) {
                    const int row = m0 + wr * 64 + fr * 16 + l4 * 4 + r;
                    Hb[(size_t)row * CDIM + col] = __float2bfloat16(fmaxf(acc[fr][fc][r] + bias, 0.f));
                }
        }
    } else {
        // blocked V write: tile = 64 rows starting at m0 + wr*64
        const int mt = m0 + wr * 64;
        const int bb = mt >> 11;                   // batch
        const int ktb = (mt & (TSEQ - 1)) >> 6;    // k-tile index
        const int hh = ((n0 - CDIM) + wc * 64) >> 6;  // head
        __hip_bfloat16* tile = Vblk + (((size_t)hh * Bb + bb) * (TSEQ / 64) + ktb) * (HS * 64);
        #pragma unroll
        for (int fc = 0; fc < 4; fc++) {
            const int d = fc * 16 + l15;
            const int c2 = hh * HS + d;
            const float bias = bv[c2];
            #pragma unroll
            for (int fr = 0; fr < 4; fr++) {
                const int tl = fr * 16 + sl4 * 4;  // sigma'd t within panel
                union { ushort4 u; __hip_bfloat16 h[4]; } o;
                #pragma unroll
                for (int r = 0; r < 4; r++) o.h[r] = __float2bfloat16(acc[fr][fc][r] + bias);
                *(ushort4*)(tile + (size_t)d * 64 + tl) = o.u;
            }
        }
    }
}

// ---------- projection GEMM: out = Y @ Wp + bp (f32 out) ----------
__global__ __launch_bounds__(256, 2)
void gemm_proj(const __hip_bfloat16* __restrict__ X, const __hip_bfloat16* __restrict__ Wt,
               const float* __restrict__ bN, float* __restrict__ Out, int M)
{
    __shared__ __align__(16) __hip_bfloat16 As[128 * 32];
    __shared__ __align__(16) __hip_bfloat16 Bs[128 * 32];
    const int tid = threadIdx.x, wave = tid >> 6, lane = tid & 63;
    const int wr = wave >> 1, wc = wave & 1, l15 = lane & 15, l4 = lane >> 4;
    const int m0 = blockIdx.y * 128, n0 = blockIdx.x * 128;
    const int K = CDIM;
    const int srow = wave * 32 + (lane >> 2), scol = (lane & 3) * 8;
    const __hip_bfloat16* xg = X + (size_t)(m0 + srow) * K + scol;
    const __hip_bfloat16* wg = Wt + (size_t)(n0 + srow) * K + scol;
    __hip_bfloat16* la = &As[wave * 32 * 32];
    __hip_bfloat16* lb = &Bs[wave * 32 * 32];

    f32x4 acc[4][4] = {};
    for (int k0 = 0; k0 < K; k0 += 32) {
        __syncthreads();
        gload16(xg + k0, la);
        gload16(xg + k0 + (size_t)16 * K, la + 16 * 32);
        gload16(wg + k0, lb);
        gload16(wg + k0 + (size_t)16 * K, lb + 16 * 32);
        __syncthreads();
        bf16x8 af[4], bfr[4];
        #pragma unroll
        for (int f = 0; f < 4; f++) af[f]  = *(const bf16x8*)&As[(wr * 64 + f * 16 + l15) * 32 + l4 * 8];
        #pragma unroll
        for (int f = 0; f < 4; f++) bfr[f] = *(const bf16x8*)&Bs[(wc * 64 + f * 16 + l15) * 32 + l4 * 8];
        #pragma unroll
        for (int fr = 0; fr < 4; fr++)
            #pragma unroll
            for (int fc = 0; fc < 4; fc++)
                acc[fr][fc] = __builtin_amdgcn_mfma_f32_16x16x32_bf16(af[fr], bfr[fc], acc[fr][fc], 0, 0, 0);
    }

    #pragma unroll
    for (int fc = 0; fc < 4; fc++) {
        const int col = n0 + wc * 64 + fc * 16 + l15;
        const float bias = bN[col];
        #pragma unroll
        for (int fr = 0; fr < 4; fr++)
            #pragma unroll
            for (int r = 0; r < 4; r++) {
                const int row = m0 + wr * 64 + fr * 16 + l4 * 4 + r;
                Out[(size_t)row * CDIM + col] = acc[fr][fc][r] + bias;
            }
    }
}

// ---------- fused synthesizer attention v9: k-split x4, 8 waves/SIMD ----------
// Block = 8 waves = 2 q-units (32 rows each, from tiles pi and 15-pi) x 4
// k-quarters. Grid 1024 = 4 blocks/CU = 32 waves/CU. Main loop unchanged
// (direct global fragments, no barriers); 2-round LDS tree combine at end.
__global__ __launch_bounds__(512, 8)
void attn_mfma9(const __hip_bfloat16* __restrict__ H, const __hip_bfloat16* __restrict__ w2t,
                const __hip_bfloat16* __restrict__ Vblk, const float* __restrict__ eb2,
                __hip_bfloat16* __restrict__ Y, int M)
{
    __shared__ float LSY[4][2][4][64][4];  // 4 slots x 8KB = 32 KB
    __shared__ float LSL[4][64];
    __shared__ float Ls[2][32];

    const int tid = threadIdx.x;
    const int w = tid >> 6, lane = tid & 63;
    const int l31 = lane & 31, hi = lane >> 5;
    const int hb = blockIdx.x;
    const int h = hb & 15, b = hb >> 4;
    const int Bb = M >> 11;
    const int pi = blockIdx.y >> 2, sg = blockIdx.y & 3;
    const int uid = w >> 2, qq = w & 3;            // unit, k-quarter
    const int qtile = uid ? (15 - pi) : pi;
    const int qw = qtile * 128 + sg * 32;          // this unit's first q row

    // H fragments (B-operand: col=lane&31=q, k=hi*8+j), in registers
    bf16x8 hf[4];
    {
        const size_t row = (size_t)(b * TSEQ + qw + l31);
        #pragma unroll
        for (int kk = 0; kk < 4; kk++)
            hf[kk] = *(const bf16x8*)(H + row * CDIM + h * HS + kk * 16 + hi * 8);
    }

    // per-lane fragment base pointers
    const __hip_bfloat16* kbase = w2t + (size_t)l31 * HS + hi * 8;
    const __hip_bfloat16* vtile0 = Vblk + (((size_t)h * Bb + b) * (TSEQ / 64)) * (HS * 64)
                                 + (size_t)l31 * 64 + hi * 8;

    f32x16 yacc[2] = {};
    float lsum = 0.f;
    const int lastkt = (qw + 31) >> 6;      // inclusive causal bound

    for (int kt = qq; kt <= lastkt; kt += 4) {
        const int k0 = kt * 64;
        const bool nomask = (k0 + 63 <= qw);
        bf16x8 pa[4];
        #pragma unroll
        for (int tf = 0; tf < 2; tf++) {
            float4 eb[4];
            #pragma unroll
            for (int g = 0; g < 4; g++)
                eb[g] = *(const float4*)(eb2 + k0 + tf * 32 + g * 8 + hi * 4);
            f32x16 st = {};
            #pragma unroll
            for (int kk = 0; kk < 4; kk++) {
                bf16x8 kf = *(const bf16x8*)(kbase + (size_t)(k0 + tf * 32) * HS + kk * 16);
                st = __builtin_amdgcn_mfma_f32_32x32x16_bf16(kf, hf[kk], st, 0, 0, 0);
            }
            const int qg = qw + l31;
            float p[16];
            #pragma unroll
            for (int r = 0; r < 16; r++) {
                float e = __expf(st[r]) * ((const float*)&eb[r >> 2])[r & 3];
                if (!nomask) {
                    const int tg = k0 + tf * 32 + (r & 3) + 8 * (r >> 2) + 4 * hi;
                    if (tg > qg) e = 0.f;
                }
                p[r] = e;
                lsum += e;
            }
            // direct pack: A-slot j of chunk ks=2tf+m <- p[8m+j] (sigma'd V aligns)
            #pragma unroll
            for (int m = 0; m < 2; m++) {
                union { unsigned d[4]; bf16x8 v; } pk;
                #pragma unroll
                for (int dw = 0; dw < 4; dw++)
                    pk.d[dw] = packbf(p[8 * m + 2 * dw], p[8 * m + 2 * dw + 1]);
                pa[tf * 2 + m] = pk.v;
            }
        }
        // PV: Y += P @ V_tile (V fragments from blocked panel)
        const __hip_bfloat16* vt = vtile0 + (size_t)kt * (HS * 64);
        #pragma unroll
        for (int ks = 0; ks < 4; ks++) {
            #pragma unroll
            for (int df = 0; df < 2; df++) {
                bf16x8 vf = *(const bf16x8*)(vt + (size_t)df * 32 * 64 + ks * 16);
                yacc[df] = __builtin_amdgcn_mfma_f32_32x32x16_bf16(pa[ks], vf, yacc[df], 0, 0, 0);
            }
        }
    }

    // ---- 2-round tree combine over the 4 k-quarters of each unit ----
    // round 1: quarters 2,3 publish
    if (qq >= 2) {
        const int slot = uid * 2 + (qq - 2);
        #pragma unroll
        for (int df = 0; df < 2; df++)
            #pragma unroll
            for (int g = 0; g < 4; g++) {
                float4 t;
                t.x = yacc[df][g * 4 + 0]; t.y = yacc[df][g * 4 + 1];
                t.z = yacc[df][g * 4 + 2]; t.w = yacc[df][g * 4 + 3];
                *(float4*)&LSY[slot][df][g][lane][0] = t;
            }
        LSL[slot][lane] = lsum;
    }
    __syncthreads();
    if (qq < 2) {
        const int slot = uid * 2 + qq;
        lsum += LSL[slot][lane];
        #pragma unroll
        for (int df = 0; df < 2; df++)
            #pragma unroll
            for (int g = 0; g < 4; g++) {
                float4 t = *(const float4*)&LSY[slot][df][g][lane][0];
                yacc[df][g * 4 + 0] += t.x; yacc[df][g * 4 + 1] += t.y;
                yacc[df][g * 4 + 2] += t.z; yacc[df][g * 4 + 3] += t.w;
            }
    }
    __syncthreads();
    // round 2: quarter 1 publishes into slot uid
    if (qq == 1) {
        #pragma unroll
        for (int df = 0; df < 2; df++)
            #pragma unroll
            for (int g = 0; g < 4; g++) {
                float4 t;
                t.x = yacc[df][g * 4 + 0]; t.y = yacc[df][g * 4 + 1];
                t.z = yacc[df][g * 4 + 2]; t.w = yacc[df][g * 4 + 3];
                *(float4*)&LSY[uid][df][g][lane][0] = t;
            }
        LSL[uid][lane] = lsum;
    }
    __syncthreads();
    if (qq == 0) {
        lsum += LSL[uid][lane];
        #pragma unroll
        for (int df = 0; df < 2; df++)
            #pragma unroll
            for (int g = 0; g < 4; g++) {
                float4 t = *(const float4*)&LSY[uid][df][g][lane][0];
                yacc[df][g * 4 + 0] += t.x; yacc[df][g * 4 + 1] += t.y;
                yacc[df][g * 4 + 2] += t.z; yacc[df][g * 4 + 3] += t.w;
            }
        lsum += __shfl_xor(lsum, 32);
        if (hi == 0) Ls[uid][l31] = lsum;

        #pragma unroll
        for (int g = 0; g < 4; g++) {
            float4 lv = *(const float4*)&Ls[uid][g * 8 + hi * 4];
            #pragma unroll
            for (int df = 0; df < 2; df++)
                #pragma unroll
                for (int rr = 0; rr < 4; rr++) {
                    const float v = yacc[df][g * 4 + rr] / ((const float*)&lv)[rr];
                    const size_t row = (size_t)(b * TSEQ + qw + 8 * g + 4 * hi + rr);
                    Y[row * CDIM + h * HS + df * 32 + l31] = __float2bfloat16(v);
                }
        }
    }
}

extern "C" void kernel_launch(void* const* d_in, const int* in_sizes, int n_in,
                              void* d_out, int out_size, void* d_ws, size_t ws_size,
                              hipStream_t stream) {
    const float* x   = (const float*)d_in[0];
    const float* W1  = (const float*)d_in[1];
    const float* bw1 = (const float*)d_in[2];
    const float* b1  = (const float*)d_in[3];
    const float* w2  = (const float*)d_in[4];
    const float* b2  = (const float*)d_in[5];
    const float* Wv  = (const float*)d_in[6];
    const float* bv  = (const float*)d_in[7];
    const float* Wp  = (const float*)d_in[8];
    const float* bp  = (const float*)d_in[9];
    float* out = (float*)d_out;

    const int B = in_sizes[0] / (TSEQ * CDIM);   // 2
    const int M = B * TSEQ;                      // 4096
    const size_t MC = (size_t)M * CDIM;          // 4M
    const size_t WC = (size_t)CDIM * CDIM;       // 1M

    __hip_bfloat16* xb  = (__hip_bfloat16*)d_ws;
    __hip_bfloat16* Wqv = xb  + MC;              // [2048][1024]: W1t then Wvt
    __hip_bfloat16* Wpt = Wqv + 2 * WC;
    __hip_bfloat16* w2t = Wpt + WC;              // [T][HS]
    __hip_bfloat16* Hb  = w2t + (size_t)TSEQ * HS;
    __hip_bfloat16* Vbk = Hb  + MC;              // blocked [h][b][kt][d][64]
    __hip_bfloat16* Yb  = Vbk + MC;
    float*          eb2 = (float*)(Yb + MC);     // exp(b2), T floats

    dim3 blk(256);
    conv_bf16<<<dim3((unsigned)(MC / 1024)), blk, 0, stream>>>(x, xb, (int)MC);
    exp_b2<<<dim3(TSEQ / 256), blk, 0, stream>>>(b2, eb2, TSEQ);
    transpose3_to_bf16<<<dim3(32, 32, 3), blk, 0, stream>>>(W1, Wv, Wp, Wqv, Wqv + WC, Wpt);
    transpose_to_bf16<<<dim3(TSEQ / 32, HS / 32), blk, 0, stream>>>(w2, w2t, HS, TSEQ);

    gemm_qv<<<dim3(16, M / 128), blk, 0, stream>>>(xb, Wqv, bw1, b1, bv, Hb, Vbk, M);

    attn_mfma9<<<dim3(16 * B, 32), dim3(512), 0, stream>>>(Hb, w2t, Vbk, eb2, Yb, M);

    gemm_proj<<<dim3(8, M / 128), blk, 0, stream>>>(Yb, Wpt, bp, out, M);
}

// Round 14
// 162.840 us; speedup vs baseline: 1.7779x; 1.7779x over previous
//
#include <hip/hip_runtime.h>
#include <hip/hip_bf16.h>

#define TSEQ 2048
#define CDIM 1024
#define NH 16
#define HS 64

typedef __attribute__((ext_vector_type(8))) short bf16x8;
typedef __attribute__((ext_vector_type(4))) float f32x4;
typedef __attribute__((ext_vector_type(16))) float f32x16;

__device__ inline void gload16(const void* g, void* l) {
    __builtin_amdgcn_global_load_lds((const __attribute__((address_space(1))) void*)g,
                                     (__attribute__((address_space(3))) void*)l, 16, 0, 0);
}

__device__ inline unsigned packbf(float a, float b) {
    union { __hip_bfloat162 h; unsigned u; } cv;
    cv.h = __float22bfloat162_rn(make_float2(a, b));
    return cv.u;
}

// ---------- elementwise f32 -> bf16 ----------
__global__ __launch_bounds__(256)
void conv_bf16(const float* __restrict__ in, __hip_bfloat16* __restrict__ out, int n) {
    int i = (blockIdx.x * 256 + threadIdx.x) * 4;
    if (i + 3 < n) {
        float4 v = *(const float4*)(in + i);
        union { ushort4 u; __hip_bfloat16 h[4]; } o;
        o.h[0] = __float2bfloat16(v.x);
        o.h[1] = __float2bfloat16(v.y);
        o.h[2] = __float2bfloat16(v.z);
        o.h[3] = __float2bfloat16(v.w);
        *(ushort4*)((unsigned short*)out + i) = o.u;
    }
}

// ---------- exp(b2) precompute ----------
__global__ __launch_bounds__(256)
void exp_b2(const float* __restrict__ b2, float* __restrict__ eb2, int n) {
    int i = blockIdx.x * 256 + threadIdx.x;
    if (i < n) eb2[i] = __expf(b2[i]);
}

// ---------- tiled transpose (+convert) : in [R][C] f32 -> out [C][R] bf16 ----------
__global__ __launch_bounds__(256)
void transpose_to_bf16(const float* __restrict__ in, __hip_bfloat16* __restrict__ out,
                       int R, int C) {
    __shared__ float t[32][33];
    const int tx = threadIdx.x & 31, ty = threadIdx.x >> 5;  // 32 x 8
    const int r0 = blockIdx.y * 32, c0 = blockIdx.x * 32;
    #pragma unroll
    for (int i = 0; i < 32; i += 8)
        t[ty + i][tx] = in[(size_t)(r0 + ty + i) * C + c0 + tx];
    __syncthreads();
    #pragma unroll
    for (int i = 0; i < 32; i += 8)
        out[(size_t)(c0 + ty + i) * R + r0 + tx] = __float2bfloat16(t[tx][ty + i]);
}

// ---------- fused 3x 1024x1024 transpose (W1, Wv, Wp) ----------
__global__ __launch_bounds__(256)
void transpose3_to_bf16(const float* __restrict__ W1, const float* __restrict__ Wv,
                        const float* __restrict__ Wp, __hip_bfloat16* __restrict__ o1,
                        __hip_bfloat16* __restrict__ o2, __hip_bfloat16* __restrict__ o3) {
    __shared__ float t[32][33];
    const float* in = blockIdx.z == 0 ? W1 : (blockIdx.z == 1 ? Wv : Wp);
    __hip_bfloat16* out = blockIdx.z == 0 ? o1 : (blockIdx.z == 1 ? o2 : o3);
    const int tx = threadIdx.x & 31, ty = threadIdx.x >> 5;
    const int r0 = blockIdx.y * 32, c0 = blockIdx.x * 32;
    #pragma unroll
    for (int i = 0; i < 32; i += 8)
        t[ty + i][tx] = in[(size_t)(r0 + ty + i) * CDIM + c0 + tx];
    __syncthreads();
    #pragma unroll
    for (int i = 0; i < 32; i += 8)
        out[(size_t)(c0 + ty + i) * CDIM + r0 + tx] = __float2bfloat16(t[tx][ty + i]);
}

// ---------- fused QV GEMM: [H | Vblk] = x @ [W1 | Wv] ----------
// H scaled by log2(e) so attention can use exp2 directly.
// V written to BLOCKED layout Vblk[h][b][kt][d][64] with sigma (swap t-bits
// 2,3) applied within each 64-panel so the attention kernel's PV B-operand
// lines up with direct-packed P fragments (no shfl).
__global__ __launch_bounds__(256, 2)
void gemm_qv(const __hip_bfloat16* __restrict__ X, const __hip_bfloat16* __restrict__ W,
             const float* __restrict__ bw1, const float* __restrict__ b1,
             const float* __restrict__ bv, __hip_bfloat16* __restrict__ Hb,
             __hip_bfloat16* __restrict__ Vblk, int M)
{
    __shared__ __align__(16) __hip_bfloat16 As[128 * 32];
    __shared__ __align__(16) __hip_bfloat16 Bs[128 * 32];
    const int tid = threadIdx.x, wave = tid >> 6, lane = tid & 63;
    const int wr = wave >> 1, wc = wave & 1, l15 = lane & 15, l4 = lane >> 4;
    const int m0 = blockIdx.y * 128, n0 = blockIdx.x * 128;
    const int K = CDIM;
    const int Bb = M >> 11;                       // batches (T=2048)
    const int srow = wave * 32 + (lane >> 2), scol = (lane & 3) * 8;
    const __hip_bfloat16* xg = X + (size_t)(m0 + srow) * K + scol;
    const __hip_bfloat16* wg = W + (size_t)(n0 + srow) * K + scol;
    __hip_bfloat16* la = &As[wave * 32 * 32];
    __hip_bfloat16* lb = &Bs[wave * 32 * 32];

    f32x4 acc[4][4] = {};
    for (int k0 = 0; k0 < K; k0 += 32) {
        __syncthreads();
        gload16(xg + k0, la);
        gload16(xg + k0 + (size_t)16 * K, la + 16 * 32);
        gload16(wg + k0, lb);
        gload16(wg + k0 + (size_t)16 * K, lb + 16 * 32);
        __syncthreads();
        bf16x8 af[4], bfr[4];
        #pragma unroll
        for (int f = 0; f < 4; f++) af[f]  = *(const bf16x8*)&As[(wr * 64 + f * 16 + l15) * 32 + l4 * 8];
        #pragma unroll
        for (int f = 0; f < 4; f++) bfr[f] = *(const bf16x8*)&Bs[(wc * 64 + f * 16 + l15) * 32 + l4 * 8];
        #pragma unroll
        for (int fr = 0; fr < 4; fr++)
            #pragma unroll
            for (int fc = 0; fc < 4; fc++)
                acc[fr][fc] = __builtin_amdgcn_mfma_f32_16x16x32_bf16(af[fr], bfr[fc], acc[fr][fc], 0, 0, 0);
    }

    const bool isH = (n0 < CDIM);
    const int sl4 = ((l4 & 1) << 1) | (l4 >> 1);   // sigma: swap t-bits 2,3
    if (isH) {
        #pragma unroll
        for (int fc = 0; fc < 4; fc++) {
            const int col = n0 + wc * 64 + fc * 16 + l15;
            const float bias = bw1[col] + b1[col & (HS - 1)];
            #pragma unroll
            for (int fr = 0; fr < 4; fr++)
                #pragma unroll
                for (int r = 0; r < 4; r++) {
                    const int row = m0 + wr * 64 + fr * 16 + l4 * 4 + r;
                    const float hv = fmaxf(acc[fr][fc][r] + bias, 0.f) * 1.44269504f;
                    Hb[(size_t)row * CDIM + col] = __float2bfloat16(hv);
                }
        }
    } else {
        // blocked V write: tile = 64 rows starting at m0 + wr*64
        const int mt = m0 + wr * 64;
        const int bb = mt >> 11;                   // batch
        const int ktb = (mt & (TSEQ - 1)) >> 6;    // k-tile index
        const int hh = ((n0 - CDIM) + wc * 64) >> 6;  // head
        __hip_bfloat16* tile = Vblk + (((size_t)hh * Bb + bb) * (TSEQ / 64) + ktb) * (HS * 64);
        #pragma unroll
        for (int fc = 0; fc < 4; fc++) {
            const int d = fc * 16 + l15;
            const int c2 = hh * HS + d;
            const float bias = bv[c2];
            #pragma unroll
            for (int fr = 0; fr < 4; fr++) {
                const int tl = fr * 16 + sl4 * 4;  // sigma'd t within panel
                union { ushort4 u; __hip_bfloat16 h[4]; } o;
                #pragma unroll
                for (int r = 0; r < 4; r++) o.h[r] = __float2bfloat16(acc[fr][fc][r] + bias);
                *(ushort4*)(tile + (size_t)d * 64 + tl) = o.u;
            }
        }
    }
}

// ---------- projection GEMM: out = Y @ Wp + bp (f32 out) ----------
__global__ __launch_bounds__(256, 2)
void gemm_proj(const __hip_bfloat16* __restrict__ X, const __hip_bfloat16* __restrict__ Wt,
               const float* __restrict__ bN, float* __restrict__ Out, int M)
{
    __shared__ __align__(16) __hip_bfloat16 As[128 * 32];
    __shared__ __align__(16) __hip_bfloat16 Bs[128 * 32];
    const int tid = threadIdx.x, wave = tid >> 6, lane = tid & 63;
    const int wr = wave >> 1, wc = wave & 1, l15 = lane & 15, l4 = lane >> 4;
    const int m0 = blockIdx.y * 128, n0 = blockIdx.x * 128;
    const int K = CDIM;
    const int srow = wave * 32 + (lane >> 2), scol = (lane & 3) * 8;
    const __hip_bfloat16* xg = X + (size_t)(m0 + srow) * K + scol;
    const __hip_bfloat16* wg = Wt + (size_t)(n0 + srow) * K + scol;
    __hip_bfloat16* la = &As[wave * 32 * 32];
    __hip_bfloat16* lb = &Bs[wave * 32 * 32];

    f32x4 acc[4][4] = {};
    for (int k0 = 0; k0 < K; k0 += 32) {
        __syncthreads();
        gload16(xg + k0, la);
        gload16(xg + k0 + (size_t)16 * K, la + 16 * 32);
        gload16(wg + k0, lb);
        gload16(wg + k0 + (size_t)16 * K, lb + 16 * 32);
        __syncthreads();
        bf16x8 af[4], bfr[4];
        #pragma unroll
        for (int f = 0; f < 4; f++) af[f]  = *(const bf16x8*)&As[(wr * 64 + f * 16 + l15) * 32 + l4 * 8];
        #pragma unroll
        for (int f = 0; f < 4; f++) bfr[f] = *(const bf16x8*)&Bs[(wc * 64 + f * 16 + l15) * 32 + l4 * 8];
        #pragma unroll
        for (int fr = 0; fr < 4; fr++)
            #pragma unroll
            for (int fc = 0; fc < 4; fc++)
                acc[fr][fc] = __builtin_amdgcn_mfma_f32_16x16x32_bf16(af[fr], bfr[fc], acc[fr][fc], 0, 0, 0);
    }

    #pragma unroll
    for (int fc = 0; fc < 4; fc++) {
        const int col = n0 + wc * 64 + fc * 16 + l15;
        const float bias = bN[col];
        #pragma unroll
        for (int fr = 0; fr < 4; fr++)
            #pragma unroll
            for (int r = 0; r < 4; r++) {
                const int row = m0 + wr * 64 + fr * 16 + l4 * 4 + r;
                Out[(size_t)row * CDIM + col] = acc[fr][fc][r] + bias;
            }
    }
}

// ---------- fused synthesizer attention v10 ----------
// Block = 256 threads (4 waves) = one 32-row q-unit; wave w owns k-quarters
// kt = w, w+4, w+8, ...  V fragments PREFETCHED one iteration ahead into
// ping-pong register sets (vfA/vfB) to hide L3 latency. K (w2t, 256KB, shared
// by ALL blocks) stays global/L2. H pre-scaled by log2e -> exp2f.
// 3 blocks/CU (VGPR-capped via launch_bounds(256,3)). LDS tree combine.

#define LOADV(DST, KT) do {                                                     \
    const __hip_bfloat16* vt_ = vtile0 + (size_t)(KT) * (HS * 64);              \
    _Pragma("unroll")                                                           \
    for (int ks_ = 0; ks_ < 4; ks_++)                                           \
        _Pragma("unroll")                                                       \
        for (int df_ = 0; df_ < 2; df_++)                                       \
            DST[ks_ * 2 + df_] = *(const bf16x8*)(vt_ + (size_t)df_ * 32 * 64 + ks_ * 16); \
} while (0)

#define ATTN_STEP(KT, VF) do {                                                  \
    const int k0_ = (KT) * 64;                                                  \
    const bool nomask_ = (k0_ + 63 <= qw);                                      \
    bf16x8 pa[4];                                                               \
    _Pragma("unroll")                                                           \
    for (int tf = 0; tf < 2; tf++) {                                            \
        float4 eb[4];                                                           \
        _Pragma("unroll")                                                       \
        for (int g = 0; g < 4; g++)                                             \
            eb[g] = *(const float4*)(eb2 + k0_ + tf * 32 + g * 8 + hi * 4);     \
        f32x16 st = {};                                                         \
        _Pragma("unroll")                                                       \
        for (int kk = 0; kk < 4; kk++) {                                        \
            bf16x8 kf = *(const bf16x8*)(kbase + (size_t)(k0_ + tf * 32) * HS + kk * 16); \
            st = __builtin_amdgcn_mfma_f32_32x32x16_bf16(kf, hf[kk], st, 0, 0, 0); \
        }                                                                       \
        const int qg_ = qw + l31;                                               \
        float p[16];                                                            \
        _Pragma("unroll")                                                       \
        for (int r = 0; r < 16; r++) {                                          \
            float e = exp2f(st[r]) * ((const float*)&eb[r >> 2])[r & 3];        \
            if (!nomask_) {                                                     \
                const int tg_ = k0_ + tf * 32 + (r & 3) + 8 * (r >> 2) + 4 * hi; \
                if (tg_ > qg_) e = 0.f;                                         \
            }                                                                   \
            p[r] = e;                                                           \
            lsum += e;                                                          \
        }                                                                       \
        _Pragma("unroll")                                                       \
        for (int m = 0; m < 2; m++) {                                           \
            union { unsigned d[4]; bf16x8 v; } pk;                              \
            _Pragma("unroll")                                                   \
            for (int dw = 0; dw < 4; dw++)                                      \
                pk.d[dw] = packbf(p[8 * m + 2 * dw], p[8 * m + 2 * dw + 1]);    \
            pa[tf * 2 + m] = pk.v;                                              \
        }                                                                       \
    }                                                                           \
    _Pragma("unroll")                                                           \
    for (int ks = 0; ks < 4; ks++) {                                            \
        _Pragma("unroll")                                                       \
        for (int df = 0; df < 2; df++)                                          \
            yacc[df] = __builtin_amdgcn_mfma_f32_32x32x16_bf16(pa[ks], VF[ks * 2 + df], yacc[df], 0, 0, 0); \
    }                                                                           \
} while (0)

__global__ __launch_bounds__(256, 3)
void attn_mfma10(const __hip_bfloat16* __restrict__ H, const __hip_bfloat16* __restrict__ w2t,
                 const __hip_bfloat16* __restrict__ Vblk, const float* __restrict__ eb2,
                 __hip_bfloat16* __restrict__ Y, int M)
{
    __shared__ float LSY[2][2][4][64][4];  // 2 slots x 8KB = 16 KB
    __shared__ float LSL[2][64];
    __shared__ float Ls[32];

    const int tid = threadIdx.x;
    const int w = tid >> 6, lane = tid & 63;   // w = k-quarter 0..3
    const int l31 = lane & 31, hi = lane >> 5;
    const int hb = blockIdx.x;
    const int h = hb & 15, b = hb >> 4;
    const int u = 63 - blockIdx.y;             // q-unit, heavy-first
    const int Bb = M >> 11;
    const int qw = u * 32;

    // H fragments (B-operand: col=lane&31=q, k=hi*8+j), in registers
    bf16x8 hf[4];
    {
        const size_t row = (size_t)(b * TSEQ + qw + l31);
        #pragma unroll
        for (int kk = 0; kk < 4; kk++)
            hf[kk] = *(const bf16x8*)(H + row * CDIM + h * HS + kk * 16 + hi * 8);
    }

    const __hip_bfloat16* kbase = w2t + (size_t)l31 * HS + hi * 8;
    const __hip_bfloat16* vtile0 = Vblk + (((size_t)h * Bb + b) * (TSEQ / 64)) * (HS * 64)
                                 + (size_t)l31 * 64 + hi * 8;

    f32x16 yacc[2] = {};
    float lsum = 0.f;
    const int lastkt = u >> 1;      // inclusive causal bound for this unit

    {
        bf16x8 vfA[8], vfB[8];
        int kt = w;
        if (kt <= lastkt) {
            LOADV(vfA, kt);
            for (;;) {
                if (kt + 4 <= lastkt) LOADV(vfB, kt + 4);
                ATTN_STEP(kt, vfA);
                kt += 4;
                if (kt > lastkt) break;
                if (kt + 4 <= lastkt) LOADV(vfA, kt + 4);
                ATTN_STEP(kt, vfB);
                kt += 4;
                if (kt > lastkt) break;
            }
        }
    }

    // ---- tree combine over the 4 k-quarters ----
    if (w >= 2) {
        const int slot = w - 2;
        #pragma unroll
        for (int df = 0; df < 2; df++)
            #pragma unroll
            for (int g = 0; g < 4; g++) {
                float4 t;
                t.x = yacc[df][g * 4 + 0]; t.y = yacc[df][g * 4 + 1];
                t.z = yacc[df][g * 4 + 2]; t.w = yacc[df][g * 4 + 3];
                *(float4*)&LSY[slot][df][g][lane][0] = t;
            }
        LSL[w - 2][lane] = lsum;
    }
    __syncthreads();
    if (w < 2) {
        lsum += LSL[w][lane];
        #pragma unroll
        for (int df = 0; df < 2; df++)
            #pragma unroll
            for (int g = 0; g < 4; g++) {
                float4 t = *(const float4*)&LSY[w][df][g][lane][0];
                yacc[df][g * 4 + 0] += t.x; yacc[df][g * 4 + 1] += t.y;
                yacc[df][g * 4 + 2] += t.z; yacc[df][g * 4 + 3] += t.w;
            }
    }
    __syncthreads();
    if (w == 1) {
        #pragma unroll
        for (int df = 0; df < 2; df++)
            #pragma unroll
            for (int g = 0; g < 4; g++) {
                float4 t;
                t.x = yacc[df][g * 4 + 0]; t.y = yacc[df][g * 4 + 1];
                t.z = yacc[df][g * 4 + 2]; t.w = yacc[df][g * 4 + 3];
                *(float4*)&LSY[0][df][g][lane][0] = t;
            }
        LSL[0][lane] = lsum;
    }
    __syncthreads();
    if (w == 0) {
        lsum += LSL[0][lane];
        #pragma unroll
        for (int df = 0; df < 2; df++)
            #pragma unroll
            for (int g = 0; g < 4; g++) {
                float4 t = *(const float4*)&LSY[0][df][g][lane][0];
                yacc[df][g * 4 + 0] += t.x; yacc[df][g * 4 + 1] += t.y;
                yacc[df][g * 4 + 2] += t.z; yacc[df][g * 4 + 3] += t.w;
            }
        lsum += __shfl_xor(lsum, 32);
        if (hi == 0) Ls[l31] = lsum;

        #pragma unroll
        for (int g = 0; g < 4; g++) {
            float4 lv = *(const float4*)&Ls[g * 8 + hi * 4];
            #pragma unroll
            for (int df = 0; df < 2; df++)
                #pragma unroll
                for (int rr = 0; rr < 4; rr++) {
                    const float v = yacc[df][g * 4 + rr] / ((const float*)&lv)[rr];
                    const size_t row = (size_t)(b * TSEQ + qw + 8 * g + 4 * hi + rr);
                    Y[row * CDIM + h * HS + df * 32 + l31] = __float2bfloat16(v);
                }
        }
    }
}

extern "C" void kernel_launch(void* const* d_in, const int* in_sizes, int n_in,
                              void* d_out, int out_size, void* d_ws, size_t ws_size,
                              hipStream_t stream) {
    const float* x   = (const float*)d_in[0];
    const float* W1  = (const float*)d_in[1];
    const float* bw1 = (const float*)d_in[2];
    const float* b1  = (const float*)d_in[3];
    const float* w2  = (const float*)d_in[4];
    const float* b2  = (const float*)d_in[5];
    const float* Wv  = (const float*)d_in[6];
    const float* bv  = (const float*)d_in[7];
    const float* Wp  = (const float*)d_in[8];
    const float* bp  = (const float*)d_in[9];
    float* out = (float*)d_out;

    const int B = in_sizes[0] / (TSEQ * CDIM);   // 2
    const int M = B * TSEQ;                      // 4096
    const size_t MC = (size_t)M * CDIM;          // 4M
    const size_t WC = (size_t)CDIM * CDIM;       // 1M

    __hip_bfloat16* xb  = (__hip_bfloat16*)d_ws;
    __hip_bfloat16* Wqv = xb  + MC;              // [2048][1024]: W1t then Wvt
    __hip_bfloat16* Wpt = Wqv + 2 * WC;
    __hip_bfloat16* w2t = Wpt + WC;              // [T][HS]
    __hip_bfloat16* Hb  = w2t + (size_t)TSEQ * HS;
    __hip_bfloat16* Vbk = Hb  + MC;              // blocked [h][b][kt][d][64]
    __hip_bfloat16* Yb  = Vbk + MC;
    float*          eb2 = (float*)(Yb + MC);     // exp(b2), T floats

    dim3 blk(256);
    conv_bf16<<<dim3((unsigned)(MC / 1024)), blk, 0, stream>>>(x, xb, (int)MC);
    exp_b2<<<dim3(TSEQ / 256), blk, 0, stream>>>(b2, eb2, TSEQ);
    transpose3_to_bf16<<<dim3(32, 32, 3), blk, 0, stream>>>(W1, Wv, Wp, Wqv, Wqv + WC, Wpt);
    transpose_to_bf16<<<dim3(TSEQ / 32, HS / 32), blk, 0, stream>>>(w2, w2t, HS, TSEQ);

    gemm_qv<<<dim3(16, M / 128), blk, 0, stream>>>(xb, Wqv, bw1, b1, bv, Hb, Vbk, M);

    attn_mfma10<<<dim3(16 * B, 64), blk, 0, stream>>>(Hb, w2t, Vbk, eb2, Yb, M);

    gemm_proj<<<dim3(8, M / 128), blk, 0, stream>>>(Yb, Wpt, bp, out, M);
}

// Round 15
// 148.005 us; speedup vs baseline: 1.9561x; 1.1002x over previous
//
#include <hip/hip_runtime.h>
#include <hip/hip_bf16.h>

#define TSEQ 2048
#define CDIM 1024
#define NH 16
#define HS 64

typedef __attribute__((ext_vector_type(8))) short bf16x8;
typedef __attribute__((ext_vector_type(4))) float f32x4;
typedef __attribute__((ext_vector_type(16))) float f32x16;

__device__ inline void gload16(const void* g, void* l) {
    __builtin_amdgcn_global_load_lds((const __attribute__((address_space(1))) void*)g,
                                     (__attribute__((address_space(3))) void*)l, 16, 0, 0);
}

__device__ inline unsigned packbf(float a, float b) {
    union { __hip_bfloat162 h; unsigned u; } cv;
    cv.h = __float22bfloat162_rn(make_float2(a, b));
    return cv.u;
}

// ---------- elementwise f32 -> bf16 ----------
__global__ __launch_bounds__(256)
void conv_bf16(const float* __restrict__ in, __hip_bfloat16* __restrict__ out, int n) {
    int i = (blockIdx.x * 256 + threadIdx.x) * 4;
    if (i + 3 < n) {
        float4 v = *(const float4*)(in + i);
        union { ushort4 u; __hip_bfloat16 h[4]; } o;
        o.h[0] = __float2bfloat16(v.x);
        o.h[1] = __float2bfloat16(v.y);
        o.h[2] = __float2bfloat16(v.z);
        o.h[3] = __float2bfloat16(v.w);
        *(ushort4*)((unsigned short*)out + i) = o.u;
    }
}

// ---------- exp(b2) precompute ----------
__global__ __launch_bounds__(256)
void exp_b2(const float* __restrict__ b2, float* __restrict__ eb2, int n) {
    int i = blockIdx.x * 256 + threadIdx.x;
    if (i < n) eb2[i] = __expf(b2[i]);
}

// ---------- tiled transpose (+convert) : in [R][C] f32 -> out [C][R] bf16 ----------
__global__ __launch_bounds__(256)
void transpose_to_bf16(const float* __restrict__ in, __hip_bfloat16* __restrict__ out,
                       int R, int C) {
    __shared__ float t[32][33];
    const int tx = threadIdx.x & 31, ty = threadIdx.x >> 5;  // 32 x 8
    const int r0 = blockIdx.y * 32, c0 = blockIdx.x * 32;
    #pragma unroll
    for (int i = 0; i < 32; i += 8)
        t[ty + i][tx] = in[(size_t)(r0 + ty + i) * C + c0 + tx];
    __syncthreads();
    #pragma unroll
    for (int i = 0; i < 32; i += 8)
        out[(size_t)(c0 + ty + i) * R + r0 + tx] = __float2bfloat16(t[tx][ty + i]);
}

// ---------- fused 3x 1024x1024 transpose (W1, Wv, Wp) ----------
__global__ __launch_bounds__(256)
void transpose3_to_bf16(const float* __restrict__ W1, const float* __restrict__ Wv,
                        const float* __restrict__ Wp, __hip_bfloat16* __restrict__ o1,
                        __hip_bfloat16* __restrict__ o2, __hip_bfloat16* __restrict__ o3) {
    __shared__ float t[32][33];
    const float* in = blockIdx.z == 0 ? W1 : (blockIdx.z == 1 ? Wv : Wp);
    __hip_bfloat16* out = blockIdx.z == 0 ? o1 : (blockIdx.z == 1 ? o2 : o3);
    const int tx = threadIdx.x & 31, ty = threadIdx.x >> 5;
    const int r0 = blockIdx.y * 32, c0 = blockIdx.x * 32;
    #pragma unroll
    for (int i = 0; i < 32; i += 8)
        t[ty + i][tx] = in[(size_t)(r0 + ty + i) * CDIM + c0 + tx];
    __syncthreads();
    #pragma unroll
    for (int i = 0; i < 32; i += 8)
        out[(size_t)(c0 + ty + i) * CDIM + r0 + tx] = __float2bfloat16(t[tx][ty + i]);
}

// ---------- fused QV GEMM: [H | Vblk] = x @ [W1 | Wv] ----------
// H scaled by log2(e) so attention can use exp2 directly.
// V written to BLOCKED layout Vblk[h][b][kt][d][64] with sigma (swap t-bits
// 2,3) applied within each 64-panel so the attention kernel's PV B-operand
// lines up with direct-packed P fragments (no shfl).
__global__ __launch_bounds__(256, 2)
void gemm_qv(const __hip_bfloat16* __restrict__ X, const __hip_bfloat16* __restrict__ W,
             const float* __restrict__ bw1, const float* __restrict__ b1,
             const float* __restrict__ bv, __hip_bfloat16* __restrict__ Hb,
             __hip_bfloat16* __restrict__ Vblk, int M)
{
    __shared__ __align__(16) __hip_bfloat16 As[128 * 32];
    __shared__ __align__(16) __hip_bfloat16 Bs[128 * 32];
    const int tid = threadIdx.x, wave = tid >> 6, lane = tid & 63;
    const int wr = wave >> 1, wc = wave & 1, l15 = lane & 15, l4 = lane >> 4;
    const int m0 = blockIdx.y * 128, n0 = blockIdx.x * 128;
    const int K = CDIM;
    const int Bb = M >> 11;                       // batches (T=2048)
    const int srow = wave * 32 + (lane >> 2), scol = (lane & 3) * 8;
    const __hip_bfloat16* xg = X + (size_t)(m0 + srow) * K + scol;
    const __hip_bfloat16* wg = W + (size_t)(n0 + srow) * K + scol;
    __hip_bfloat16* la = &As[wave * 32 * 32];
    __hip_bfloat16* lb = &Bs[wave * 32 * 32];

    f32x4 acc[4][4] = {};
    for (int k0 = 0; k0 < K; k0 += 32) {
        __syncthreads();
        gload16(xg + k0, la);
        gload16(xg + k0 + (size_t)16 * K, la + 16 * 32);
        gload16(wg + k0, lb);
        gload16(wg + k0 + (size_t)16 * K, lb + 16 * 32);
        __syncthreads();
        bf16x8 af[4], bfr[4];
        #pragma unroll
        for (int f = 0; f < 4; f++) af[f]  = *(const bf16x8*)&As[(wr * 64 + f * 16 + l15) * 32 + l4 * 8];
        #pragma unroll
        for (int f = 0; f < 4; f++) bfr[f] = *(const bf16x8*)&Bs[(wc * 64 + f * 16 + l15) * 32 + l4 * 8];
        #pragma unroll
        for (int fr = 0; fr < 4; fr++)
            #pragma unroll
            for (int fc = 0; fc < 4; fc++)
                acc[fr][fc] = __builtin_amdgcn_mfma_f32_16x16x32_bf16(af[fr], bfr[fc], acc[fr][fc], 0, 0, 0);
    }

    const bool isH = (n0 < CDIM);
    const int sl4 = ((l4 & 1) << 1) | (l4 >> 1);   // sigma: swap t-bits 2,3
    if (isH) {
        #pragma unroll
        for (int fc = 0; fc < 4; fc++) {
            const int col = n0 + wc * 64 + fc * 16 + l15;
            const float bias = bw1[col] + b1[col & (HS - 1)];
            #pragma unroll
            for (int fr = 0; fr < 4; fr++)
                #pragma unroll
                for (int r = 0; r < 4; r++) {
                    const int row = m0 + wr * 64 + fr * 16 + l4 * 4 + r;
                    const float hv = fmaxf(acc[fr][fc][r] + bias, 0.f) * 1.44269504f;
                    Hb[(size_t)row * CDIM + col] = __float2bfloat16(hv);
                }
        }
    } else {
        // blocked V write: tile = 64 rows starting at m0 + wr*64
        const int mt = m0 + wr * 64;
        const int bb = mt >> 11;                   // batch
        const int ktb = (mt & (TSEQ - 1)) >> 6;    // k-tile index
        const int hh = ((n0 - CDIM) + wc * 64) >> 6;  // head
        __hip_bfloat16* tile = Vblk + (((size_t)hh * Bb + bb) * (TSEQ / 64) + ktb) * (HS * 64);
        #pragma unroll
        for (int fc = 0; fc < 4; fc++) {
            const int d = fc * 16 + l15;
            const int c2 = hh * HS + d;
            const float bias = bv[c2];
            #pragma unroll
            for (int fr = 0; fr < 4; fr++) {
                const int tl = fr * 16 + sl4 * 4;  // sigma'd t within panel
                union { ushort4 u; __hip_bfloat16 h[4]; } o;
                #pragma unroll
                for (int r = 0; r < 4; r++) o.h[r] = __float2bfloat16(acc[fr][fc][r] + bias);
                *(ushort4*)(tile + (size_t)d * 64 + tl) = o.u;
            }
        }
    }
}

// ---------- projection GEMM: out = Y @ Wp + bp (f32 out) ----------
__global__ __launch_bounds__(256, 2)
void gemm_proj(const __hip_bfloat16* __restrict__ X, const __hip_bfloat16* __restrict__ Wt,
               const float* __restrict__ bN, float* __restrict__ Out, int M)
{
    __shared__ __align__(16) __hip_bfloat16 As[128 * 32];
    __shared__ __align__(16) __hip_bfloat16 Bs[128 * 32];
    const int tid = threadIdx.x, wave = tid >> 6, lane = tid & 63;
    const int wr = wave >> 1, wc = wave & 1, l15 = lane & 15, l4 = lane >> 4;
    const int m0 = blockIdx.y * 128, n0 = blockIdx.x * 128;
    const int K = CDIM;
    const int srow = wave * 32 + (lane >> 2), scol = (lane & 3) * 8;
    const __hip_bfloat16* xg = X + (size_t)(m0 + srow) * K + scol;
    const __hip_bfloat16* wg = Wt + (size_t)(n0 + srow) * K + scol;
    __hip_bfloat16* la = &As[wave * 32 * 32];
    __hip_bfloat16* lb = &Bs[wave * 32 * 32];

    f32x4 acc[4][4] = {};
    for (int k0 = 0; k0 < K; k0 += 32) {
        __syncthreads();
        gload16(xg + k0, la);
        gload16(xg + k0 + (size_t)16 * K, la + 16 * 32);
        gload16(wg + k0, lb);
        gload16(wg + k0 + (size_t)16 * K, lb + 16 * 32);
        __syncthreads();
        bf16x8 af[4], bfr[4];
        #pragma unroll
        for (int f = 0; f < 4; f++) af[f]  = *(const bf16x8*)&As[(wr * 64 + f * 16 + l15) * 32 + l4 * 8];
        #pragma unroll
        for (int f = 0; f < 4; f++) bfr[f] = *(const bf16x8*)&Bs[(wc * 64 + f * 16 + l15) * 32 + l4 * 8];
        #pragma unroll
        for (int fr = 0; fr < 4; fr++)
            #pragma unroll
            for (int fc = 0; fc < 4; fc++)
                acc[fr][fc] = __builtin_amdgcn_mfma_f32_16x16x32_bf16(af[fr], bfr[fc], acc[fr][fc], 0, 0, 0);
    }

    #pragma unroll
    for (int fc = 0; fc < 4; fc++) {
        const int col = n0 + wc * 64 + fc * 16 + l15;
        const float bias = bN[col];
        #pragma unroll
        for (int fr = 0; fr < 4; fr++)
            #pragma unroll
            for (int r = 0; r < 4; r++) {
                const int row = m0 + wr * 64 + fr * 16 + l4 * 4 + r;
                Out[(size_t)row * CDIM + col] = acc[fr][fc][r] + bias;
            }
    }
}

// ---------- fused synthesizer attention v11: r8 LDS-dbuf + direct pack ----------
// Block = 4 waves x 32 q rows (q-tile 128, causal-paired). K and sigma'd V
// tiles double-buffered in LDS via coalesced global_load_lds (XOR-swizzled
// via pre-swizzled SOURCE address, linear LDS dest). Direct P pack (sigma in
// Vblk memory), eb2 from global, exp2f (H pre-scaled by log2e).
#define STAGEKV(KT, BUF) do {                                                   \
    gload16(kg0 + (size_t)(KT) * (64 * HS), &Ks[BUF][(w * 16) * 64]);           \
    gload16(kg1 + (size_t)(KT) * (64 * HS), &Ks[BUF][(w * 16 + 8) * 64]);       \
    gload16(vg0 + (size_t)(KT) * (HS * 64), &Vs[BUF][(w * 16) * 64]);           \
    gload16(vg1 + (size_t)(KT) * (HS * 64), &Vs[BUF][(w * 16 + 8) * 64]);       \
} while (0)

__global__ __launch_bounds__(256, 2)
void attn_mfma11(const __hip_bfloat16* __restrict__ H, const __hip_bfloat16* __restrict__ w2t,
                 const __hip_bfloat16* __restrict__ Vblk, const float* __restrict__ eb2,
                 __hip_bfloat16* __restrict__ Y, int M)
{
    __shared__ __align__(16) __hip_bfloat16 Ks[2][64 * 64];  // [t][hs], swizzled
    __shared__ __align__(16) __hip_bfloat16 Vs[2][64 * 64];  // [d][t sigma], swizzled
    __shared__ float Ls[4 * 32];

    const int tid = threadIdx.x;
    const int w = tid >> 6, lane = tid & 63;
    const int l31 = lane & 31, hi = lane >> 5;
    const int h = blockIdx.y, b = blockIdx.z;
    const int u = (blockIdx.x + blockIdx.y) & 15;
    const int qb = b ? (15 - u) : u;        // causal load-balance pairing
    const int q0 = qb * 128;
    const int qw = q0 + w * 32;             // this wave's first q row
    const int swz = l31 & 7;
    const int Bb = M >> 11;

    // staging geometry: wave w stages rows w*16 .. w*16+15 of each tile
    const int srr = lane >> 3, spc = lane & 7;
    const int sr0 = w * 16 + srr, sr1 = sr0 + 8;
    const int sc = (spc ^ srr) * 8;          // pre-XOR source chunk ((sr&7)==srr)
    const __hip_bfloat16* kg0 = w2t + (size_t)sr0 * HS + sc;
    const __hip_bfloat16* kg1 = w2t + (size_t)sr1 * HS + sc;
    const __hip_bfloat16* vpan = Vblk + (((size_t)h * Bb + b) * (TSEQ / 64)) * (HS * 64);
    const __hip_bfloat16* vg0 = vpan + (size_t)sr0 * 64 + sc;
    const __hip_bfloat16* vg1 = vpan + (size_t)sr1 * 64 + sc;

    // H fragments (B-operand: col=lane&31=q, k=hi*8+j), in registers
    bf16x8 hf[4];
    {
        const size_t row = (size_t)(b * TSEQ + qw + l31);
        #pragma unroll
        for (int kk = 0; kk < 4; kk++)
            hf[kk] = *(const bf16x8*)(H + row * CDIM + h * HS + kk * 16 + hi * 8);
    }

    f32x16 yacc[2] = {};
    float lsum = 0.f;
    const int ntile = 2 * qb + 2;

    STAGEKV(0, 0);
    __syncthreads();

    int cur = 0;
    for (int kt = 0; kt < ntile; kt++) {
        const int k0 = kt * 64;
        if (kt + 1 < ntile) STAGEKV(kt + 1, cur ^ 1);   // async, overlaps compute
        if (k0 <= qw + 31) {
            const bool nomask = (k0 + 63 <= qw);
            bf16x8 pa[4];
            #pragma unroll
            for (int tf = 0; tf < 2; tf++) {
                float4 eb[4];
                #pragma unroll
                for (int g = 0; g < 4; g++)
                    eb[g] = *(const float4*)(eb2 + k0 + tf * 32 + g * 8 + hi * 4);
                f32x16 st = {};
                #pragma unroll
                for (int kk = 0; kk < 4; kk++) {
                    const int cs = (kk * 2 + hi) ^ swz;
                    bf16x8 kf = *(const bf16x8*)((const char*)&Ks[cur][0] + (tf * 32 + l31) * 128 + cs * 16);
                    st = __builtin_amdgcn_mfma_f32_32x32x16_bf16(kf, hf[kk], st, 0, 0, 0);
                }
                const int qg = qw + l31;
                float p[16];
                #pragma unroll
                for (int r = 0; r < 16; r++) {
                    float e = exp2f(st[r]) * ((const float*)&eb[r >> 2])[r & 3];
                    if (!nomask) {
                        const int tg = k0 + tf * 32 + (r & 3) + 8 * (r >> 2) + 4 * hi;
                        if (tg > qg) e = 0.f;
                    }
                    p[r] = e;
                    lsum += e;
                }
                // direct pack: A-slot j of chunk ks=2tf+m <- p[8m+j] (sigma'd V aligns)
                #pragma unroll
                for (int m = 0; m < 2; m++) {
                    union { unsigned d[4]; bf16x8 v; } pk;
                    #pragma unroll
                    for (int dw = 0; dw < 4; dw++)
                        pk.d[dw] = packbf(p[8 * m + 2 * dw], p[8 * m + 2 * dw + 1]);
                    pa[tf * 2 + m] = pk.v;
                }
            }
            // PV: Y += P @ V_tile (V fragments from swizzled LDS)
            #pragma unroll
            for (int ks = 0; ks < 4; ks++) {
                const int cs = (ks * 2 + hi) ^ swz;
                #pragma unroll
                for (int df = 0; df < 2; df++) {
                    bf16x8 vf = *(const bf16x8*)((const char*)&Vs[cur][0] + (df * 32 + l31) * 128 + cs * 16);
                    yacc[df] = __builtin_amdgcn_mfma_f32_32x32x16_bf16(pa[ks], vf, yacc[df], 0, 0, 0);
                }
            }
        }
        __syncthreads();   // drains staging loads; releases cur buffer
        cur ^= 1;
    }

    // combine the two k-halves (hi 0/1) of each q-row sum, publish per-wave
    lsum += __shfl_xor(lsum, 32);
    if (hi == 0) Ls[w * 32 + l31] = lsum;
    __syncthreads();

    #pragma unroll
    for (int g = 0; g < 4; g++) {
        float4 lv = *(const float4*)&Ls[w * 32 + g * 8 + hi * 4];
        #pragma unroll
        for (int df = 0; df < 2; df++)
            #pragma unroll
            for (int rr = 0; rr < 4; rr++) {
                const float v = yacc[df][g * 4 + rr] / ((const float*)&lv)[rr];
                const size_t row = (size_t)(b * TSEQ + qw + 8 * g + 4 * hi + rr);
                Y[row * CDIM + h * HS + df * 32 + l31] = __float2bfloat16(v);
            }
    }
}

extern "C" void kernel_launch(void* const* d_in, const int* in_sizes, int n_in,
                              void* d_out, int out_size, void* d_ws, size_t ws_size,
                              hipStream_t stream) {
    const float* x   = (const float*)d_in[0];
    const float* W1  = (const float*)d_in[1];
    const float* bw1 = (const float*)d_in[2];
    const float* b1  = (const float*)d_in[3];
    const float* w2  = (const float*)d_in[4];
    const float* b2  = (const float*)d_in[5];
    const float* Wv  = (const float*)d_in[6];
    const float* bv  = (const float*)d_in[7];
    const float* Wp  = (const float*)d_in[8];
    const float* bp  = (const float*)d_in[9];
    float* out = (float*)d_out;

    const int B = in_sizes[0] / (TSEQ * CDIM);   // 2
    const int M = B * TSEQ;                      // 4096
    const size_t MC = (size_t)M * CDIM;          // 4M
    const size_t WC = (size_t)CDIM * CDIM;       // 1M

    __hip_bfloat16* xb  = (__hip_bfloat16*)d_ws;
    __hip_bfloat16* Wqv = xb  + MC;              // [2048][1024]: W1t then Wvt
    __hip_bfloat16* Wpt = Wqv + 2 * WC;
    __hip_bfloat16* w2t = Wpt + WC;              // [T][HS]
    __hip_bfloat16* Hb  = w2t + (size_t)TSEQ * HS;
    __hip_bfloat16* Vbk = Hb  + MC;              // blocked [h][b][kt][d][64]
    __hip_bfloat16* Yb  = Vbk + MC;
    float*          eb2 = (float*)(Yb + MC);     // exp(b2), T floats

    dim3 blk(256);
    conv_bf16<<<dim3((unsigned)(MC / 1024)), blk, 0, stream>>>(x, xb, (int)MC);
    exp_b2<<<dim3(TSEQ / 256), blk, 0, stream>>>(b2, eb2, TSEQ);
    transpose3_to_bf16<<<dim3(32, 32, 3), blk, 0, stream>>>(W1, Wv, Wp, Wqv, Wqv + WC, Wpt);
    transpose_to_bf16<<<dim3(TSEQ / 32, HS / 32), blk, 0, stream>>>(w2, w2t, HS, TSEQ);

    gemm_qv<<<dim3(16, M / 128), blk, 0, stream>>>(xb, Wqv, bw1, b1, bv, Hb, Vbk, M);

    attn_mfma11<<<dim3(16, NH, B), blk, 0, stream>>>(Hb, w2t, Vbk, eb2, Yb, M);

    gemm_proj<<<dim3(8, M / 128), blk, 0, stream>>>(Yb, Wpt, bp, out, M);
}

// Round 16
// 137.252 us; speedup vs baseline: 2.1094x; 1.0784x over previous
//
#include <hip/hip_runtime.h>
#include <hip/hip_bf16.h>

#define TSEQ 2048
#define CDIM 1024
#define NH 16
#define HS 64

typedef __attribute__((ext_vector_type(8))) short bf16x8;
typedef __attribute__((ext_vector_type(4))) float f32x4;
typedef __attribute__((ext_vector_type(16))) float f32x16;

__device__ inline void gload16(const void* g, void* l) {
    __builtin_amdgcn_global_load_lds((const __attribute__((address_space(1))) void*)g,
                                     (__attribute__((address_space(3))) void*)l, 16, 0, 0);
}

__device__ inline unsigned packbf(float a, float b) {
    union { __hip_bfloat162 h; unsigned u; } cv;
    cv.h = __float22bfloat162_rn(make_float2(a, b));
    return cv.u;
}

// ---------- elementwise f32 -> bf16 ----------
__global__ __launch_bounds__(256)
void conv_bf16(const float* __restrict__ in, __hip_bfloat16* __restrict__ out, int n) {
    int i = (blockIdx.x * 256 + threadIdx.x) * 4;
    if (i + 3 < n) {
        float4 v = *(const float4*)(in + i);
        union { ushort4 u; __hip_bfloat16 h[4]; } o;
        o.h[0] = __float2bfloat16(v.x);
        o.h[1] = __float2bfloat16(v.y);
        o.h[2] = __float2bfloat16(v.z);
        o.h[3] = __float2bfloat16(v.w);
        *(ushort4*)((unsigned short*)out + i) = o.u;
    }
}

// ---------- exp(b2) precompute ----------
__global__ __launch_bounds__(256)
void exp_b2(const float* __restrict__ b2, float* __restrict__ eb2, int n) {
    int i = blockIdx.x * 256 + threadIdx.x;
    if (i < n) eb2[i] = __expf(b2[i]);
}

// ---------- tiled transpose (+convert) : in [R][C] f32 -> out [C][R] bf16 ----------
__global__ __launch_bounds__(256)
void transpose_to_bf16(const float* __restrict__ in, __hip_bfloat16* __restrict__ out,
                       int R, int C) {
    __shared__ float t[32][33];
    const int tx = threadIdx.x & 31, ty = threadIdx.x >> 5;  // 32 x 8
    const int r0 = blockIdx.y * 32, c0 = blockIdx.x * 32;
    #pragma unroll
    for (int i = 0; i < 32; i += 8)
        t[ty + i][tx] = in[(size_t)(r0 + ty + i) * C + c0 + tx];
    __syncthreads();
    #pragma unroll
    for (int i = 0; i < 32; i += 8)
        out[(size_t)(c0 + ty + i) * R + r0 + tx] = __float2bfloat16(t[tx][ty + i]);
}

// ---------- fused 3x 1024x1024 transpose (W1, Wv, Wp) ----------
__global__ __launch_bounds__(256)
void transpose3_to_bf16(const float* __restrict__ W1, const float* __restrict__ Wv,
                        const float* __restrict__ Wp, __hip_bfloat16* __restrict__ o1,
                        __hip_bfloat16* __restrict__ o2, __hip_bfloat16* __restrict__ o3) {
    __shared__ float t[32][33];
    const float* in = blockIdx.z == 0 ? W1 : (blockIdx.z == 1 ? Wv : Wp);
    __hip_bfloat16* out = blockIdx.z == 0 ? o1 : (blockIdx.z == 1 ? o2 : o3);
    const int tx = threadIdx.x & 31, ty = threadIdx.x >> 5;
    const int r0 = blockIdx.y * 32, c0 = blockIdx.x * 32;
    #pragma unroll
    for (int i = 0; i < 32; i += 8)
        t[ty + i][tx] = in[(size_t)(r0 + ty + i) * CDIM + c0 + tx];
    __syncthreads();
    #pragma unroll
    for (int i = 0; i < 32; i += 8)
        out[(size_t)(c0 + ty + i) * CDIM + r0 + tx] = __float2bfloat16(t[tx][ty + i]);
}

// ---------- fused QV GEMM: [H | Vblk] = x @ [W1 | Wv] ----------
// H scaled by log2(e) so attention can use native exp2 directly.
// V written to BLOCKED layout Vblk[h][b][kt][d][64] with sigma (swap t-bits
// 2,3) applied within each 64-panel so the attention kernel's PV B-operand
// lines up with direct-packed P fragments (no shfl).
__global__ __launch_bounds__(256, 2)
void gemm_qv(const __hip_bfloat16* __restrict__ X, const __hip_bfloat16* __restrict__ W,
             const float* __restrict__ bw1, const float* __restrict__ b1,
             const float* __restrict__ bv, __hip_bfloat16* __restrict__ Hb,
             __hip_bfloat16* __restrict__ Vblk, int M)
{
    __shared__ __align__(16) __hip_bfloat16 As[128 * 32];
    __shared__ __align__(16) __hip_bfloat16 Bs[128 * 32];
    const int tid = threadIdx.x, wave = tid >> 6, lane = tid & 63;
    const int wr = wave >> 1, wc = wave & 1, l15 = lane & 15, l4 = lane >> 4;
    const int m0 = blockIdx.y * 128, n0 = blockIdx.x * 128;
    const int K = CDIM;
    const int Bb = M >> 11;                       // batches (T=2048)
    const int srow = wave * 32 + (lane >> 2), scol = (lane & 3) * 8;
    const __hip_bfloat16* xg = X + (size_t)(m0 + srow) * K + scol;
    const __hip_bfloat16* wg = W + (size_t)(n0 + srow) * K + scol;
    __hip_bfloat16* la = &As[wave * 32 * 32];
    __hip_bfloat16* lb = &Bs[wave * 32 * 32];

    f32x4 acc[4][4] = {};
    for (int k0 = 0; k0 < K; k0 += 32) {
        __syncthreads();
        gload16(xg + k0, la);
        gload16(xg + k0 + (size_t)16 * K, la + 16 * 32);
        gload16(wg + k0, lb);
        gload16(wg + k0 + (size_t)16 * K, lb + 16 * 32);
        __syncthreads();
        bf16x8 af[4], bfr[4];
        #pragma unroll
        for (int f = 0; f < 4; f++) af[f]  = *(const bf16x8*)&As[(wr * 64 + f * 16 + l15) * 32 + l4 * 8];
        #pragma unroll
        for (int f = 0; f < 4; f++) bfr[f] = *(const bf16x8*)&Bs[(wc * 64 + f * 16 + l15) * 32 + l4 * 8];
        #pragma unroll
        for (int fr = 0; fr < 4; fr++)
            #pragma unroll
            for (int fc = 0; fc < 4; fc++)
                acc[fr][fc] = __builtin_amdgcn_mfma_f32_16x16x32_bf16(af[fr], bfr[fc], acc[fr][fc], 0, 0, 0);
    }

    const bool isH = (n0 < CDIM);
    const int sl4 = ((l4 & 1) << 1) | (l4 >> 1);   // sigma: swap t-bits 2,3
    if (isH) {
        #pragma unroll
        for (int fc = 0; fc < 4; fc++) {
            const int col = n0 + wc * 64 + fc * 16 + l15;
            const float bias = bw1[col] + b1[col & (HS - 1)];
            #pragma unroll
            for (int fr = 0; fr < 4; fr++)
                #pragma unroll
                for (int r = 0; r < 4; r++) {
                    const int row = m0 + wr * 64 + fr * 16 + l4 * 4 + r;
                    const float hv = fmaxf(acc[fr][fc][r] + bias, 0.f) * 1.44269504f;
                    Hb[(size_t)row * CDIM + col] = __float2bfloat16(hv);
                }
        }
    } else {
        // blocked V write: tile = 64 rows starting at m0 + wr*64
        const int mt = m0 + wr * 64;
        const int bb = mt >> 11;                   // batch
        const int ktb = (mt & (TSEQ - 1)) >> 6;    // k-tile index
        const int hh = ((n0 - CDIM) + wc * 64) >> 6;  // head
        __hip_bfloat16* tile = Vblk + (((size_t)hh * Bb + bb) * (TSEQ / 64) + ktb) * (HS * 64);
        #pragma unroll
        for (int fc = 0; fc < 4; fc++) {
            const int d = fc * 16 + l15;
            const int c2 = hh * HS + d;
            const float bias = bv[c2];
            #pragma unroll
            for (int fr = 0; fr < 4; fr++) {
                const int tl = fr * 16 + sl4 * 4;  // sigma'd t within panel
                union { ushort4 u; __hip_bfloat16 h[4]; } o;
                #pragma unroll
                for (int r = 0; r < 4; r++) o.h[r] = __float2bfloat16(acc[fr][fc][r] + bias);
                *(ushort4*)(tile + (size_t)d * 64 + tl) = o.u;
            }
        }
    }
}

// ---------- projection GEMM: out = Y @ Wp + bp (f32 out) ----------
__global__ __launch_bounds__(256, 2)
void gemm_proj(const __hip_bfloat16* __restrict__ X, const __hip_bfloat16* __restrict__ Wt,
               const float* __restrict__ bN, float* __restrict__ Out, int M)
{
    __shared__ __align__(16) __hip_bfloat16 As[128 * 32];
    __shared__ __align__(16) __hip_bfloat16 Bs[128 * 32];
    const int tid = threadIdx.x, wave = tid >> 6, lane = tid & 63;
    const int wr = wave >> 1, wc = wave & 1, l15 = lane & 15, l4 = lane >> 4;
    const int m0 = blockIdx.y * 128, n0 = blockIdx.x * 128;
    const int K = CDIM;
    const int srow = wave * 32 + (lane >> 2), scol = (lane & 3) * 8;
    const __hip_bfloat16* xg = X + (size_t)(m0 + srow) * K + scol;
    const __hip_bfloat16* wg = Wt + (size_t)(n0 + srow) * K + scol;
    __hip_bfloat16* la = &As[wave * 32 * 32];
    __hip_bfloat16* lb = &Bs[wave * 32 * 32];

    f32x4 acc[4][4] = {};
    for (int k0 = 0; k0 < K; k0 += 32) {
        __syncthreads();
        gload16(xg + k0, la);
        gload16(xg + k0 + (size_t)16 * K, la + 16 * 32);
        gload16(wg + k0, lb);
        gload16(wg + k0 + (size_t)16 * K, lb + 16 * 32);
        __syncthreads();
        bf16x8 af[4], bfr[4];
        #pragma unroll
        for (int f = 0; f < 4; f++) af[f]  = *(const bf16x8*)&As[(wr * 64 + f * 16 + l15) * 32 + l4 * 8];
        #pragma unroll
        for (int f = 0; f < 4; f++) bfr[f] = *(const bf16x8*)&Bs[(wc * 64 + f * 16 + l15) * 32 + l4 * 8];
        #pragma unroll
        for (int fr = 0; fr < 4; fr++)
            #pragma unroll
            for (int fc = 0; fc < 4; fc++)
                acc[fr][fc] = __builtin_amdgcn_mfma_f32_16x16x32_bf16(af[fr], bfr[fc], acc[fr][fc], 0, 0, 0);
    }

    #pragma unroll
    for (int fc = 0; fc < 4; fc++) {
        const int col = n0 + wc * 64 + fc * 16 + l15;
        const float bias = bN[col];
        #pragma unroll
        for (int fr = 0; fr < 4; fr++)
            #pragma unroll
            for (int r = 0; r < 4; r++) {
                const int row = m0 + wr * 64 + fr * 16 + l4 * 4 + r;
                Out[(size_t)row * CDIM + col] = acc[fr][fc][r] + bias;
            }
    }
}

// ---------- fused synthesizer attention v12: v11 + NATIVE exp2 ----------
// Identical to v11 except exp2f (libm, ~10 VALU ops) -> __builtin_amdgcn_exp2f
// (single v_exp_f32). H is pre-scaled by log2e in gemm_qv.
#define STAGEKV(KT, BUF) do {                                                   \
    gload16(kg0 + (size_t)(KT) * (64 * HS), &Ks[BUF][(w * 16) * 64]);           \
    gload16(kg1 + (size_t)(KT) * (64 * HS), &Ks[BUF][(w * 16 + 8) * 64]);       \
    gload16(vg0 + (size_t)(KT) * (HS * 64), &Vs[BUF][(w * 16) * 64]);           \
    gload16(vg1 + (size_t)(KT) * (HS * 64), &Vs[BUF][(w * 16 + 8) * 64]);       \
} while (0)

__global__ __launch_bounds__(256, 2)
void attn_mfma12(const __hip_bfloat16* __restrict__ H, const __hip_bfloat16* __restrict__ w2t,
                 const __hip_bfloat16* __restrict__ Vblk, const float* __restrict__ eb2,
                 __hip_bfloat16* __restrict__ Y, int M)
{
    __shared__ __align__(16) __hip_bfloat16 Ks[2][64 * 64];  // [t][hs], swizzled
    __shared__ __align__(16) __hip_bfloat16 Vs[2][64 * 64];  // [d][t sigma], swizzled
    __shared__ float Ls[4 * 32];

    const int tid = threadIdx.x;
    const int w = tid >> 6, lane = tid & 63;
    const int l31 = lane & 31, hi = lane >> 5;
    const int h = blockIdx.y, b = blockIdx.z;
    const int u = (blockIdx.x + blockIdx.y) & 15;
    const int qb = b ? (15 - u) : u;        // causal load-balance pairing
    const int q0 = qb * 128;
    const int qw = q0 + w * 32;             // this wave's first q row
    const int swz = l31 & 7;
    const int Bb = M >> 11;

    // staging geometry: wave w stages rows w*16 .. w*16+15 of each tile
    const int srr = lane >> 3, spc = lane & 7;
    const int sr0 = w * 16 + srr, sr1 = sr0 + 8;
    const int sc = (spc ^ srr) * 8;          // pre-XOR source chunk ((sr&7)==srr)
    const __hip_bfloat16* kg0 = w2t + (size_t)sr0 * HS + sc;
    const __hip_bfloat16* kg1 = w2t + (size_t)sr1 * HS + sc;
    const __hip_bfloat16* vpan = Vblk + (((size_t)h * Bb + b) * (TSEQ / 64)) * (HS * 64);
    const __hip_bfloat16* vg0 = vpan + (size_t)sr0 * 64 + sc;
    const __hip_bfloat16* vg1 = vpan + (size_t)sr1 * 64 + sc;

    // H fragments (B-operand: col=lane&31=q, k=hi*8+j), in registers
    bf16x8 hf[4];
    {
        const size_t row = (size_t)(b * TSEQ + qw + l31);
        #pragma unroll
        for (int kk = 0; kk < 4; kk++)
            hf[kk] = *(const bf16x8*)(H + row * CDIM + h * HS + kk * 16 + hi * 8);
    }

    f32x16 yacc[2] = {};
    float lsum = 0.f;
    const int ntile = 2 * qb + 2;

    STAGEKV(0, 0);
    __syncthreads();

    int cur = 0;
    for (int kt = 0; kt < ntile; kt++) {
        const int k0 = kt * 64;
        if (kt + 1 < ntile) STAGEKV(kt + 1, cur ^ 1);   // async, overlaps compute
        if (k0 <= qw + 31) {
            const bool nomask = (k0 + 63 <= qw);
            bf16x8 pa[4];
            #pragma unroll
            for (int tf = 0; tf < 2; tf++) {
                float4 eb[4];
                #pragma unroll
                for (int g = 0; g < 4; g++)
                    eb[g] = *(const float4*)(eb2 + k0 + tf * 32 + g * 8 + hi * 4);
                f32x16 st = {};
                #pragma unroll
                for (int kk = 0; kk < 4; kk++) {
                    const int cs = (kk * 2 + hi) ^ swz;
                    bf16x8 kf = *(const bf16x8*)((const char*)&Ks[cur][0] + (tf * 32 + l31) * 128 + cs * 16);
                    st = __builtin_amdgcn_mfma_f32_32x32x16_bf16(kf, hf[kk], st, 0, 0, 0);
                }
                const int qg = qw + l31;
                float p[16];
                #pragma unroll
                for (int r = 0; r < 16; r++) {
                    float e = __builtin_amdgcn_exp2f(st[r]) * ((const float*)&eb[r >> 2])[r & 3];
                    if (!nomask) {
                        const int tg = k0 + tf * 32 + (r & 3) + 8 * (r >> 2) + 4 * hi;
                        if (tg > qg) e = 0.f;
                    }
                    p[r] = e;
                    lsum += e;
                }
                // direct pack: A-slot j of chunk ks=2tf+m <- p[8m+j] (sigma'd V aligns)
                #pragma unroll
                for (int m = 0; m < 2; m++) {
                    union { unsigned d[4]; bf16x8 v; } pk;
                    #pragma unroll
                    for (int dw = 0; dw < 4; dw++)
                        pk.d[dw] = packbf(p[8 * m + 2 * dw], p[8 * m + 2 * dw + 1]);
                    pa[tf * 2 + m] = pk.v;
                }
            }
            // PV: Y += P @ V_tile (V fragments from swizzled LDS)
            #pragma unroll
            for (int ks = 0; ks < 4; ks++) {
                const int cs = (ks * 2 + hi) ^ swz;
                #pragma unroll
                for (int df = 0; df < 2; df++) {
                    bf16x8 vf = *(const bf16x8*)((const char*)&Vs[cur][0] + (df * 32 + l31) * 128 + cs * 16);
                    yacc[df] = __builtin_amdgcn_mfma_f32_32x32x16_bf16(pa[ks], vf, yacc[df], 0, 0, 0);
                }
            }
        }
        __syncthreads();   // drains staging loads; releases cur buffer
        cur ^= 1;
    }

    // combine the two k-halves (hi 0/1) of each q-row sum, publish per-wave
    lsum += __shfl_xor(lsum, 32);
    if (hi == 0) Ls[w * 32 + l31] = lsum;
    __syncthreads();

    #pragma unroll
    for (int g = 0; g < 4; g++) {
        float4 lv = *(const float4*)&Ls[w * 32 + g * 8 + hi * 4];
        #pragma unroll
        for (int df = 0; df < 2; df++)
            #pragma unroll
            for (int rr = 0; rr < 4; rr++) {
                const float v = yacc[df][g * 4 + rr] / ((const float*)&lv)[rr];
                const size_t row = (size_t)(b * TSEQ + qw + 8 * g + 4 * hi + rr);
                Y[row * CDIM + h * HS + df * 32 + l31] = __float2bfloat16(v);
            }
    }
}

extern "C" void kernel_launch(void* const* d_in, const int* in_sizes, int n_in,
                              void* d_out, int out_size, void* d_ws, size_t ws_size,
                              hipStream_t stream) {
    const float* x   = (const float*)d_in[0];
    const float* W1  = (const float*)d_in[1];
    const float* bw1 = (const float*)d_in[2];
    const float* b1  = (const float*)d_in[3];
    const float* w2  = (const float*)d_in[4];
    const float* b2  = (const float*)d_in[5];
    const float* Wv  = (const float*)d_in[6];
    const float* bv  = (const float*)d_in[7];
    const float* Wp  = (const float*)d_in[8];
    const float* bp  = (const float*)d_in[9];
    float* out = (float*)d_out;

    const int B = in_sizes[0] / (TSEQ * CDIM);   // 2
    const int M = B * TSEQ;                      // 4096
    const size_t MC = (size_t)M * CDIM;          // 4M
    const size_t WC = (size_t)CDIM * CDIM;       // 1M

    __hip_bfloat16* xb  = (__hip_bfloat16*)d_ws;
    __hip_bfloat16* Wqv = xb  + MC;              // [2048][1024]: W1t then Wvt
    __hip_bfloat16* Wpt = Wqv + 2 * WC;
    __hip_bfloat16* w2t = Wpt + WC;              // [T][HS]
    __hip_bfloat16* Hb  = w2t + (size_t)TSEQ * HS;
    __hip_bfloat16* Vbk = Hb  + MC;              // blocked [h][b][kt][d][64]
    __hip_bfloat16* Yb  = Vbk + MC;
    float*          eb2 = (float*)(Yb + MC);     // exp(b2), T floats

    dim3 blk(256);
    conv_bf16<<<dim3((unsigned)(MC / 1024)), blk, 0, stream>>>(x, xb, (int)MC);
    exp_b2<<<dim3(TSEQ / 256), blk, 0, stream>>>(b2, eb2, TSEQ);
    transpose3_to_bf16<<<dim3(32, 32, 3), blk, 0, stream>>>(W1, Wv, Wp, Wqv, Wqv + WC, Wpt);
    transpose_to_bf16<<<dim3(TSEQ / 32, HS / 32), blk, 0, stream>>>(w2, w2t, HS, TSEQ);

    gemm_qv<<<dim3(16, M / 128), blk, 0, stream>>>(xb, Wqv, bw1, b1, bv, Hb, Vbk, M);

    attn_mfma12<<<dim3(16, NH, B), blk, 0, stream>>>(Hb, w2t, Vbk, eb2, Yb, M);

    gemm_proj<<<dim3(8, M / 128), blk, 0, stream>>>(Yb, Wpt, bp, out, M);
}

// Round 17
// 122.378 us; speedup vs baseline: 2.3658x; 1.1215x over previous
//
#include <hip/hip_runtime.h>
#include <hip/hip_bf16.h>

#define TSEQ 2048
#define CDIM 1024
#define NH 16
#define HS 64

typedef __attribute__((ext_vector_type(8))) short bf16x8;
typedef __attribute__((ext_vector_type(4))) float f32x4;
typedef __attribute__((ext_vector_type(16))) float f32x16;

__device__ inline void gload16(const void* g, void* l) {
    __builtin_amdgcn_global_load_lds((const __attribute__((address_space(1))) void*)g,
                                     (__attribute__((address_space(3))) void*)l, 16, 0, 0);
}

__device__ inline unsigned packbf(float a, float b) {
    union { __hip_bfloat162 h; unsigned u; } cv;
    cv.h = __float22bfloat162_rn(make_float2(a, b));
    return cv.u;
}

// ---------- elementwise f32 -> bf16 ----------
__global__ __launch_bounds__(256)
void conv_bf16(const float* __restrict__ in, __hip_bfloat16* __restrict__ out, int n) {
    int i = (blockIdx.x * 256 + threadIdx.x) * 4;
    if (i + 3 < n) {
        float4 v = *(const float4*)(in + i);
        union { ushort4 u; __hip_bfloat16 h[4]; } o;
        o.h[0] = __float2bfloat16(v.x);
        o.h[1] = __float2bfloat16(v.y);
        o.h[2] = __float2bfloat16(v.z);
        o.h[3] = __float2bfloat16(v.w);
        *(ushort4*)((unsigned short*)out + i) = o.u;
    }
}

// ---------- b2 * log2(e) precompute (bias folded into MFMA C-init) ----------
__global__ __launch_bounds__(256)
void b2_log2e(const float* __restrict__ b2, float* __restrict__ bl, int n) {
    int i = blockIdx.x * 256 + threadIdx.x;
    if (i < n) bl[i] = b2[i] * 1.44269504f;
}

// ---------- tiled transpose (+convert) : in [R][C] f32 -> out [C][R] bf16 ----------
__global__ __launch_bounds__(256)
void transpose_to_bf16(const float* __restrict__ in, __hip_bfloat16* __restrict__ out,
                       int R, int C) {
    __shared__ float t[32][33];
    const int tx = threadIdx.x & 31, ty = threadIdx.x >> 5;  // 32 x 8
    const int r0 = blockIdx.y * 32, c0 = blockIdx.x * 32;
    #pragma unroll
    for (int i = 0; i < 32; i += 8)
        t[ty + i][tx] = in[(size_t)(r0 + ty + i) * C + c0 + tx];
    __syncthreads();
    #pragma unroll
    for (int i = 0; i < 32; i += 8)
        out[(size_t)(c0 + ty + i) * R + r0 + tx] = __float2bfloat16(t[tx][ty + i]);
}

// ---------- fused 3x 1024x1024 transpose (W1, Wv, Wp) ----------
__global__ __launch_bounds__(256)
void transpose3_to_bf16(const float* __restrict__ W1, const float* __restrict__ Wv,
                        const float* __restrict__ Wp, __hip_bfloat16* __restrict__ o1,
                        __hip_bfloat16* __restrict__ o2, __hip_bfloat16* __restrict__ o3) {
    __shared__ float t[32][33];
    const float* in = blockIdx.z == 0 ? W1 : (blockIdx.z == 1 ? Wv : Wp);
    __hip_bfloat16* out = blockIdx.z == 0 ? o1 : (blockIdx.z == 1 ? o2 : o3);
    const int tx = threadIdx.x & 31, ty = threadIdx.x >> 5;
    const int r0 = blockIdx.y * 32, c0 = blockIdx.x * 32;
    #pragma unroll
    for (int i = 0; i < 32; i += 8)
        t[ty + i][tx] = in[(size_t)(r0 + ty + i) * CDIM + c0 + tx];
    __syncthreads();
    #pragma unroll
    for (int i = 0; i < 32; i += 8)
        out[(size_t)(c0 + ty + i) * CDIM + r0 + tx] = __float2bfloat16(t[tx][ty + i]);
}

// ---------- fused QV GEMM: [H | Vblk] = x @ [W1 | Wv] ----------
// H scaled by log2(e) so attention can use native exp2 directly.
// V written to BLOCKED layout Vblk[h][b][kt][d][64] with sigma (swap t-bits
// 2,3) applied within each 64-panel so the attention kernel's PV B-operand
// lines up with direct-packed P fragments (no shfl).
__global__ __launch_bounds__(256, 2)
void gemm_qv(const __hip_bfloat16* __restrict__ X, const __hip_bfloat16* __restrict__ W,
             const float* __restrict__ bw1, const float* __restrict__ b1,
             const float* __restrict__ bv, __hip_bfloat16* __restrict__ Hb,
             __hip_bfloat16* __restrict__ Vblk, int M)
{
    __shared__ __align__(16) __hip_bfloat16 As[128 * 32];
    __shared__ __align__(16) __hip_bfloat16 Bs[128 * 32];
    const int tid = threadIdx.x, wave = tid >> 6, lane = tid & 63;
    const int wr = wave >> 1, wc = wave & 1, l15 = lane & 15, l4 = lane >> 4;
    const int m0 = blockIdx.y * 128, n0 = blockIdx.x * 128;
    const int K = CDIM;
    const int Bb = M >> 11;                       // batches (T=2048)
    const int srow = wave * 32 + (lane >> 2), scol = (lane & 3) * 8;
    const __hip_bfloat16* xg = X + (size_t)(m0 + srow) * K + scol;
    const __hip_bfloat16* wg = W + (size_t)(n0 + srow) * K + scol;
    __hip_bfloat16* la = &As[wave * 32 * 32];
    __hip_bfloat16* lb = &Bs[wave * 32 * 32];

    f32x4 acc[4][4] = {};
    for (int k0 = 0; k0 < K; k0 += 32) {
        __syncthreads();
        gload16(xg + k0, la);
        gload16(xg + k0 + (size_t)16 * K, la + 16 * 32);
        gload16(wg + k0, lb);
        gload16(wg + k0 + (size_t)16 * K, lb + 16 * 32);
        __syncthreads();
        bf16x8 af[4], bfr[4];
        #pragma unroll
        for (int f = 0; f < 4; f++) af[f]  = *(const bf16x8*)&As[(wr * 64 + f * 16 + l15) * 32 + l4 * 8];
        #pragma unroll
        for (int f = 0; f < 4; f++) bfr[f] = *(const bf16x8*)&Bs[(wc * 64 + f * 16 + l15) * 32 + l4 * 8];
        #pragma unroll
        for (int fr = 0; fr < 4; fr++)
            #pragma unroll
            for (int fc = 0; fc < 4; fc++)
                acc[fr][fc] = __builtin_amdgcn_mfma_f32_16x16x32_bf16(af[fr], bfr[fc], acc[fr][fc], 0, 0, 0);
    }

    const bool isH = (n0 < CDIM);
    const int sl4 = ((l4 & 1) << 1) | (l4 >> 1);   // sigma: swap t-bits 2,3
    if (isH) {
        #pragma unroll
        for (int fc = 0; fc < 4; fc++) {
            const int col = n0 + wc * 64 + fc * 16 + l15;
            const float bias = bw1[col] + b1[col & (HS - 1)];
            #pragma unroll
            for (int fr = 0; fr < 4; fr++)
                #pragma unroll
                for (int r = 0; r < 4; r++) {
                    const int row = m0 + wr * 64 + fr * 16 + l4 * 4 + r;
                    const float hv = fmaxf(acc[fr][fc][r] + bias, 0.f) * 1.44269504f;
                    Hb[(size_t)row * CDIM + col] = __float2bfloat16(hv);
                }
        }
    } else {
        // blocked V write: tile = 64 rows starting at m0 + wr*64
        const int mt = m0 + wr * 64;
        const int bb = mt >> 11;                   // batch
        const int ktb = (mt & (TSEQ - 1)) >> 6;    // k-tile index
        const int hh = ((n0 - CDIM) + wc * 64) >> 6;  // head
        __hip_bfloat16* tile = Vblk + (((size_t)hh * Bb + bb) * (TSEQ / 64) + ktb) * (HS * 64);
        #pragma unroll
        for (int fc = 0; fc < 4; fc++) {
            const int d = fc * 16 + l15;
            const int c2 = hh * HS + d;
            const float bias = bv[c2];
            #pragma unroll
            for (int fr = 0; fr < 4; fr++) {
                const int tl = fr * 16 + sl4 * 4;  // sigma'd t within panel
                union { ushort4 u; __hip_bfloat16 h[4]; } o;
                #pragma unroll
                for (int r = 0; r < 4; r++) o.h[r] = __float2bfloat16(acc[fr][fc][r] + bias);
                *(ushort4*)(tile + (size_t)d * 64 + tl) = o.u;
            }
        }
    }
}

// ---------- projection GEMM: out = Y @ Wp + bp (f32 out) ----------
__global__ __launch_bounds__(256, 2)
void gemm_proj(const __hip_bfloat16* __restrict__ X, const __hip_bfloat16* __restrict__ Wt,
               const float* __restrict__ bN, float* __restrict__ Out, int M)
{
    __shared__ __align__(16) __hip_bfloat16 As[128 * 32];
    __shared__ __align__(16) __hip_bfloat16 Bs[128 * 32];
    const int tid = threadIdx.x, wave = tid >> 6, lane = tid & 63;
    const int wr = wave >> 1, wc = wave & 1, l15 = lane & 15, l4 = lane >> 4;
    const int m0 = blockIdx.y * 128, n0 = blockIdx.x * 128;
    const int K = CDIM;
    const int srow = wave * 32 + (lane >> 2), scol = (lane & 3) * 8;
    const __hip_bfloat16* xg = X + (size_t)(m0 + srow) * K + scol;
    const __hip_bfloat16* wg = Wt + (size_t)(n0 + srow) * K + scol;
    __hip_bfloat16* la = &As[wave * 32 * 32];
    __hip_bfloat16* lb = &Bs[wave * 32 * 32];

    f32x4 acc[4][4] = {};
    for (int k0 = 0; k0 < K; k0 += 32) {
        __syncthreads();
        gload16(xg + k0, la);
        gload16(xg + k0 + (size_t)16 * K, la + 16 * 32);
        gload16(wg + k0, lb);
        gload16(wg + k0 + (size_t)16 * K, lb + 16 * 32);
        __syncthreads();
        bf16x8 af[4], bfr[4];
        #pragma unroll
        for (int f = 0; f < 4; f++) af[f]  = *(const bf16x8*)&As[(wr * 64 + f * 16 + l15) * 32 + l4 * 8];
        #pragma unroll
        for (int f = 0; f < 4; f++) bfr[f] = *(const bf16x8*)&Bs[(wc * 64 + f * 16 + l15) * 32 + l4 * 8];
        #pragma unroll
        for (int fr = 0; fr < 4; fr++)
            #pragma unroll
            for (int fc = 0; fc < 4; fc++)
                acc[fr][fc] = __builtin_amdgcn_mfma_f32_16x16x32_bf16(af[fr], bfr[fc], acc[fr][fc], 0, 0, 0);
    }

    #pragma unroll
    for (int fc = 0; fc < 4; fc++) {
        const int col = n0 + wc * 64 + fc * 16 + l15;
        const float bias = bN[col];
        #pragma unroll
        for (int fr = 0; fr < 4; fr++)
            #pragma unroll
            for (int r = 0; r < 4; r++) {
                const int row = m0 + wr * 64 + fr * 16 + l4 * 4 + r;
                Out[(size_t)row * CDIM + col] = acc[fr][fc][r] + bias;
            }
    }
}

// ---------- fused synthesizer attention v13: counted-vmcnt pipeline ----------
// Triple-buffered K/V staged via global_load_lds; raw s_barrier + counted
// s_waitcnt vmcnt(N) so staging loads stay in flight across barriers (never
// drained to 0 in the loop). b2*log2e table staged to LDS once; bias folded
// into the QK MFMA C-init (exp2 needs no multiply). Direct sigma P-pack.
#define STAGEKV(KT, BUF) do {                                                   \
    gload16(kg0 + (size_t)(KT) * (64 * HS), &Ks[BUF][(w * 16) * 64]);           \
    gload16(kg1 + (size_t)(KT) * (64 * HS), &Ks[BUF][(w * 16 + 8) * 64]);       \
    gload16(vg0 + (size_t)(KT) * (HS * 64), &Vs[BUF][(w * 16) * 64]);           \
    gload16(vg1 + (size_t)(KT) * (HS * 64), &Vs[BUF][(w * 16 + 8) * 64]);       \
} while (0)

__global__ __launch_bounds__(256, 2)
void attn_mfma13(const __hip_bfloat16* __restrict__ H, const __hip_bfloat16* __restrict__ w2t,
                 const __hip_bfloat16* __restrict__ Vblk, const float* __restrict__ bl,
                 __hip_bfloat16* __restrict__ Y, int M)
{
    __shared__ __align__(16) __hip_bfloat16 Ks[3][64 * 64];  // [t][hs], swizzled
    __shared__ __align__(16) __hip_bfloat16 Vs[3][64 * 64];  // [d][t sigma], swizzled
    __shared__ __align__(16) float bls[TSEQ];                // b2*log2e table (8KB)
    __shared__ float Ls[4 * 32];

    const int tid = threadIdx.x;
    const int w = tid >> 6, lane = tid & 63;
    const int l31 = lane & 31, hi = lane >> 5;
    const int h = blockIdx.y, b = blockIdx.z;
    const int u = (blockIdx.x + blockIdx.y) & 15;
    const int qb = b ? (15 - u) : u;        // causal load-balance pairing
    const int q0 = qb * 128;
    const int qw = q0 + w * 32;             // this wave's first q row
    const int swz = l31 & 7;
    const int Bb = M >> 11;

    // staging geometry: wave w stages rows w*16 .. w*16+15 of each tile
    const int srr = lane >> 3, spc = lane & 7;
    const int sr0 = w * 16 + srr, sr1 = sr0 + 8;
    const int sc = (spc ^ srr) * 8;          // pre-XOR source chunk ((sr&7)==srr)
    const __hip_bfloat16* kg0 = w2t + (size_t)sr0 * HS + sc;
    const __hip_bfloat16* kg1 = w2t + (size_t)sr1 * HS + sc;
    const __hip_bfloat16* vpan = Vblk + (((size_t)h * Bb + b) * (TSEQ / 64)) * (HS * 64);
    const __hip_bfloat16* vg0 = vpan + (size_t)sr0 * 64 + sc;
    const __hip_bfloat16* vg1 = vpan + (size_t)sr1 * 64 + sc;

    // stage bl table (wave-uniform LDS base; HW adds lane*16)
    gload16(bl + (size_t)(w * 64 + lane) * 4 - (size_t)lane * 4 + (size_t)lane * 4, &bls[w * 256]);
    gload16(bl + 1024 + (size_t)w * 256 + lane * 4 - (size_t)lane * 4 + (size_t)lane * 4, &bls[1024 + w * 256]);

    // H fragments (B-operand: col=lane&31=q, k=hi*8+j), in registers
    bf16x8 hf[4];
    {
        const size_t row = (size_t)(b * TSEQ + qw + l31);
        #pragma unroll
        for (int kk = 0; kk < 4; kk++)
            hf[kk] = *(const bf16x8*)(H + row * CDIM + h * HS + kk * 16 + hi * 8);
    }

    f32x16 yacc[2] = {};
    float lsum = 0.f;
    const int ntile = 2 * qb + 2;

    STAGEKV(0, 0);
    STAGEKV(1, 1);

    for (int kt = 0; kt < ntile; kt++) {
        const int k0 = kt * 64;
        // own S(kt) complete (only S(kt+1)'s 4 loads may remain outstanding)
        if (kt + 1 < ntile) asm volatile("s_waitcnt vmcnt(4)" ::: "memory");
        else                asm volatile("s_waitcnt vmcnt(0)" ::: "memory");
        __builtin_amdgcn_s_barrier();      // all waves' S(kt) landed
        __builtin_amdgcn_sched_barrier(0);
        if (kt + 2 < ntile) STAGEKV(kt + 2, (kt + 2) % 3);  // deep prefetch
        if (k0 <= qw + 31) {
            const int buf = kt % 3;
            const bool nomask = (k0 + 63 <= qw);
            bf16x8 pa[4];
            #pragma unroll
            for (int tf = 0; tf < 2; tf++) {
                // C-init = bias*log2e (broadcast LDS reads, conflict-free)
                f32x16 st;
                #pragma unroll
                for (int g = 0; g < 4; g++) {
                    float4 blv = *(const float4*)&bls[k0 + tf * 32 + g * 8 + hi * 4];
                    st[g * 4 + 0] = blv.x; st[g * 4 + 1] = blv.y;
                    st[g * 4 + 2] = blv.z; st[g * 4 + 3] = blv.w;
                }
                #pragma unroll
                for (int kk = 0; kk < 4; kk++) {
                    const int cs = (kk * 2 + hi) ^ swz;
                    bf16x8 kf = *(const bf16x8*)((const char*)&Ks[buf][0] + (tf * 32 + l31) * 128 + cs * 16);
                    st = __builtin_amdgcn_mfma_f32_32x32x16_bf16(kf, hf[kk], st, 0, 0, 0);
                }
                const int qg = qw + l31;
                float p[16];
                #pragma unroll
                for (int r = 0; r < 16; r++) {
                    float e = __builtin_amdgcn_exp2f(st[r]);
                    if (!nomask) {
                        const int tg = k0 + tf * 32 + (r & 3) + 8 * (r >> 2) + 4 * hi;
                        if (tg > qg) e = 0.f;
                    }
                    p[r] = e;
                    lsum += e;
                }
                // direct pack: A-slot j of chunk ks=2tf+m <- p[8m+j] (sigma'd V aligns)
                #pragma unroll
                for (int m = 0; m < 2; m++) {
                    union { unsigned d[4]; bf16x8 v; } pk;
                    #pragma unroll
                    for (int dw = 0; dw < 4; dw++)
                        pk.d[dw] = packbf(p[8 * m + 2 * dw], p[8 * m + 2 * dw + 1]);
                    pa[tf * 2 + m] = pk.v;
                }
            }
            // PV: Y += P @ V_tile (V fragments from swizzled LDS)
            #pragma unroll
            for (int ks = 0; ks < 4; ks++) {
                const int cs = (ks * 2 + hi) ^ swz;
                #pragma unroll
                for (int df = 0; df < 2; df++) {
                    bf16x8 vf = *(const bf16x8*)((const char*)&Vs[buf][0] + (df * 32 + l31) * 128 + cs * 16);
                    yacc[df] = __builtin_amdgcn_mfma_f32_32x32x16_bf16(pa[ks], vf, yacc[df], 0, 0, 0);
                }
            }
        }
    }
    __syncthreads();

    // combine the two k-halves (hi 0/1) of each q-row sum, publish per-wave
    lsum += __shfl_xor(lsum, 32);
    if (hi == 0) Ls[w * 32 + l31] = lsum;
    __syncthreads();

    #pragma unroll
    for (int g = 0; g < 4; g++) {
        float4 lv = *(const float4*)&Ls[w * 32 + g * 8 + hi * 4];
        #pragma unroll
        for (int df = 0; df < 2; df++)
            #pragma unroll
            for (int rr = 0; rr < 4; rr++) {
                const float v = yacc[df][g * 4 + rr] / ((const float*)&lv)[rr];
                const size_t row = (size_t)(b * TSEQ + qw + 8 * g + 4 * hi + rr);
                Y[row * CDIM + h * HS + df * 32 + l31] = __float2bfloat16(v);
            }
    }
}

extern "C" void kernel_launch(void* const* d_in, const int* in_sizes, int n_in,
                              void* d_out, int out_size, void* d_ws, size_t ws_size,
                              hipStream_t stream) {
    const float* x   = (const float*)d_in[0];
    const float* W1  = (const float*)d_in[1];
    const float* bw1 = (const float*)d_in[2];
    const float* b1  = (const float*)d_in[3];
    const float* w2  = (const float*)d_in[4];
    const float* b2  = (const float*)d_in[5];
    const float* Wv  = (const float*)d_in[6];
    const float* bv  = (const float*)d_in[7];
    const float* Wp  = (const float*)d_in[8];
    const float* bp  = (const float*)d_in[9];
    float* out = (float*)d_out;

    const int B = in_sizes[0] / (TSEQ * CDIM);   // 2
    const int M = B * TSEQ;                      // 4096
    const size_t MC = (size_t)M * CDIM;          // 4M
    const size_t WC = (size_t)CDIM * CDIM;       // 1M

    __hip_bfloat16* xb  = (__hip_bfloat16*)d_ws;
    __hip_bfloat16* Wqv = xb  + MC;              // [2048][1024]: W1t then Wvt
    __hip_bfloat16* Wpt = Wqv + 2 * WC;
    __hip_bfloat16* w2t = Wpt + WC;              // [T][HS]
    __hip_bfloat16* Hb  = w2t + (size_t)TSEQ * HS;
    __hip_bfloat16* Vbk = Hb  + MC;              // blocked [h][b][kt][d][64]
    __hip_bfloat16* Yb  = Vbk + MC;
    float*          bl  = (float*)(Yb + MC);     // b2*log2e, T floats

    dim3 blk(256);
    conv_bf16<<<dim3((unsigned)(MC / 1024)), blk, 0, stream>>>(x, xb, (int)MC);
    b2_log2e<<<dim3(TSEQ / 256), blk, 0, stream>>>(b2, bl, TSEQ);
    transpose3_to_bf16<<<dim3(32, 32, 3), blk, 0, stream>>>(W1, Wv, Wp, Wqv, Wqv + WC, Wpt);
    transpose_to_bf16<<<dim3(TSEQ / 32, HS / 32), blk, 0, stream>>>(w2, w2t, HS, TSEQ);

    gemm_qv<<<dim3(16, M / 128), blk, 0, stream>>>(xb, Wqv, bw1, b1, bv, Hb, Vbk, M);

    attn_mfma13<<<dim3(16, NH, B), blk, 0, stream>>>(Hb, w2t, Vbk, bl, Yb, M);

    gemm_proj<<<dim3(8, M / 128), blk, 0, stream>>>(Yb, Wpt, bp, out, M);
}